// Round 14
// baseline (85.217 us; speedup 1.0000x reference)
//
#include <hip/hip_runtime.h>
#include <hip/hip_bf16.h>
#include <math.h>

// Problem constants
#define NN 8
#define CC 256
#define LL 1024
#define EE 512
#define HEADS 8
#define DH 64

// Workspace float offsets
#define OFF_STYLE   0u          // 2048
#define OFF_BIAS    2048u       // 1536
#define OFF_COS     3584u       // 32768
#define OFF_SIN     36352u      // 32768
#define OFF_WQB     69120u      // bf16 1536*256 -> 196608 floats
#define OFF_WPB     265728u     // bf16 256*512  -> 65536 floats
#define OFF_XMT     331264u     // bf16 8*1024*256 -> 1048576 floats
#define OFF_Q       1379840u    // bf16 64*1024*64 -> 2097152 floats
#define OFF_K       3476992u
#define OFF_V       5574144u    // bf16 transposed [head][d][l]
#define OFF_O       7671296u    // bf16 [n][l][512] -> 2097152 floats
// total 9768448 floats = 39.1 MB

typedef __bf16 bf16x8 __attribute__((ext_vector_type(8)));
typedef __bf16 bf16x4 __attribute__((ext_vector_type(4)));
typedef short s16x4 __attribute__((ext_vector_type(4)));
typedef short s16x8 __attribute__((ext_vector_type(8)));
typedef float f32x4 __attribute__((ext_vector_type(4)));

// ---------------- fused prep: wq-norm | wp-norm | rope | style in one launch ----------------
__global__ __launch_bounds__(256) void k_prep(
    const float* __restrict__ w, const float* __restrict__ mod_w, float* __restrict__ style,
    const float* __restrict__ qkv_w, const float* __restrict__ gain,
    const float* __restrict__ bias, __hip_bfloat16* __restrict__ wqb, float* __restrict__ biasg,
    const float* __restrict__ proj_w, const float* __restrict__ rgain,
    __hip_bfloat16* __restrict__ wpb,
    float* __restrict__ cosT, float* __restrict__ sinT) {
    int bid = blockIdx.x;
    int t = threadIdx.x;
    int wv = t >> 6, lane = t & 63;
    if (bid < 384) {
        int o = bid * 4 + wv;
        float4 v = *reinterpret_cast<const float4*>(qkv_w + o * CC + lane * 4);
        float s = v.x + v.y + v.z + v.w;
        #pragma unroll
        for (int off = 1; off < 64; off <<= 1) s += __shfl_xor(s, off);
        float mean = s * (1.0f / 256.0f);
        float c0 = v.x - mean, c1 = v.y - mean, c2 = v.z - mean, c3 = v.w - mean;
        float ss = c0 * c0 + c1 * c1 + c2 * c2 + c3 * c3;
        #pragma unroll
        for (int off = 1; off < 64; off <<= 1) ss += __shfl_xor(ss, off);
        float g = gain[o];
        float scale = g / ((sqrtf(ss) + 1e-8f) * 16.0f);
        bf16x4 outv;
        outv[0] = (__bf16)(c0 * scale); outv[1] = (__bf16)(c1 * scale);
        outv[2] = (__bf16)(c2 * scale); outv[3] = (__bf16)(c3 * scale);
        *reinterpret_cast<bf16x4*>((__bf16*)wqb + o * CC + lane * 4) = outv;
        if (lane == 0) biasg[o] = bias[o] * g;
    } else if (bid < 448) {
        int r = (bid - 384) * 4 + wv;
        const float* p = proj_w + r * 512 + lane * 8;
        float4 v0 = *reinterpret_cast<const float4*>(p);
        float4 v1 = *reinterpret_cast<const float4*>(p + 4);
        float s = v0.x + v0.y + v0.z + v0.w + v1.x + v1.y + v1.z + v1.w;
        #pragma unroll
        for (int off = 1; off < 64; off <<= 1) s += __shfl_xor(s, off);
        float mean = s * (1.0f / 512.0f);
        float c[8] = {v0.x - mean, v0.y - mean, v0.z - mean, v0.w - mean,
                      v1.x - mean, v1.y - mean, v1.z - mean, v1.w - mean};
        float ss = 0.f;
        #pragma unroll
        for (int i = 0; i < 8; ++i) ss += c[i] * c[i];
        #pragma unroll
        for (int off = 1; off < 64; off <<= 1) ss += __shfl_xor(ss, off);
        float scale = rgain[r] / ((sqrtf(ss) + 1e-8f) * 22.62741699796952f);
        bf16x8 outv;
        #pragma unroll
        for (int i = 0; i < 8; ++i) outv[i] = (__bf16)(c[i] * scale);
        *reinterpret_cast<bf16x8*>((__bf16*)wpb + r * 512 + lane * 8) = outv;
    } else if (bid < 512) {
        int idx = (bid - 448) * 256 + t;
        int l = idx >> 4, j = idx & 15;
        int hh = l >> 5, ww = l & 31;
        float f = exp2f(-(float)j * 0.8304820238941836f);
        float s1, c1, s2, c2;
        __sincosf((float)hh * f, &s1, &c1);
        __sincosf((float)ww * f, &s2, &c2);
        cosT[l * 32 + j]      = c1;
        sinT[l * 32 + j]      = s1;
        cosT[l * 32 + 16 + j] = c2;
        sinT[l * 32 + 16 + j] = s2;
    } else {
        int b = bid - 512;
        int n = b >> 2, cg = b & 3;
        int c = cg * 64 + lane;
        __shared__ float red[4][64];
        float acc = 0.f;
        #pragma unroll 8
        for (int e = wv * 128; e < wv * 128 + 128; ++e)
            acc += w[n * EE + e] * mod_w[e * CC + c];
        red[wv][lane] = acc;
        __syncthreads();
        if (wv == 0)
            style[n * CC + c] = red[0][lane] + red[1][lane] + red[2][lane] + red[3][lane] + 1.0f;
    }
}

// ------------- prep: xmT[n][l][c] = bf16(x[n][c][l] * style[n][c]) -------------
__global__ __launch_bounds__(256) void k_xm(const float* __restrict__ x,
                                            const float* __restrict__ style,
                                            __hip_bfloat16* __restrict__ xmT) {
    int lb = blockIdx.x;   // 16
    int cb = blockIdx.y;   // 4
    int n  = blockIdx.z;   // 8
    int t = threadIdx.x;
    __shared__ float tile[64][68];
    int r = t >> 2, q = t & 3;
    float st = style[n * CC + cb * 64 + r];
    const float* xp = x + (size_t)n * (CC * LL) + (size_t)(cb * 64 + r) * LL + lb * 64 + q * 16;
    #pragma unroll
    for (int i = 0; i < 4; ++i) {
        float4 v = *reinterpret_cast<const float4*>(xp + i * 4);
        tile[r][q * 16 + i * 4 + 0] = v.x * st;
        tile[r][q * 16 + i * 4 + 1] = v.y * st;
        tile[r][q * 16 + i * 4 + 2] = v.z * st;
        tile[r][q * 16 + i * 4 + 3] = v.w * st;
    }
    __syncthreads();
    __hip_bfloat16 outv[16];
    #pragma unroll
    for (int i = 0; i < 16; ++i)
        outv[i] = __float2bfloat16(tile[q * 16 + i][r]);
    __hip_bfloat16* dst = xmT + (size_t)n * (LL * CC) + (size_t)(lb * 64 + r) * CC + cb * 64 + q * 16;
    *reinterpret_cast<bf16x8*>(dst)     = *reinterpret_cast<bf16x8*>(&outv[0]);
    *reinterpret_cast<bf16x8*>(dst + 8) = *reinterpret_cast<bf16x8*>(&outv[8]);
}

// ------------- QKV MFMA GEMM, LDS-staged, single-barrier dbuf + fused epilogue -------------
__global__ __launch_bounds__(256) void k_qkv3(const __hip_bfloat16* __restrict__ wqb,
                                              const __hip_bfloat16* __restrict__ xmT,
                                              const float* __restrict__ biasg,
                                              const float* __restrict__ cosT,
                                              const float* __restrict__ sinT,
                                              __hip_bfloat16* __restrict__ qb,
                                              __hip_bfloat16* __restrict__ kb,
                                              __hip_bfloat16* __restrict__ vt) {
    int lb = blockIdx.x;   // 8
    int ob = blockIdx.y;   // 12
    int n  = blockIdx.z;   // 8
    int tid = threadIdx.x;
    int wid = tid >> 6, lane = tid & 63;
    int wr = wid >> 1, wc = wid & 1;
    int g = lane >> 4, r16 = lane & 15;

    int o0 = ob * 128 + wr * 64;
    int l0 = lb * 128 + wc * 64;
    int part = o0 >> 9;
    int h = (o0 & 511) >> 6;

    __shared__ __hip_bfloat16 smem[32768];

    const int srow[4] = {tid >> 3, (tid + 256) >> 3, (tid + 512) >> 3, (tid + 768) >> 3};
    const int scol = (tid & 7) * 8;
    int sswz[4];
    #pragma unroll
    for (int i = 0; i < 4; ++i) sswz[i] = scol ^ ((srow[i] & 7) << 3);

    const __hip_bfloat16* Agl = wqb + (size_t)(ob * 128) * CC;
    const __hip_bfloat16* Bgl = xmT + (size_t)n * (LL * CC) + (size_t)(lb * 128) * CC;

    bf16x8 ar[4], br[4];
    #pragma unroll
    for (int i = 0; i < 4; ++i) {
        ar[i] = *reinterpret_cast<const bf16x8*>(Agl + (size_t)srow[i] * CC + scol);
        br[i] = *reinterpret_cast<const bf16x8*>(Bgl + (size_t)srow[i] * CC + scol);
    }
    #pragma unroll
    for (int i = 0; i < 4; ++i) {
        *reinterpret_cast<bf16x8*>(&smem[srow[i] * 64 + sswz[i]]) = ar[i];
        *reinterpret_cast<bf16x8*>(&smem[16384 + srow[i] * 64 + sswz[i]]) = br[i];
    }
    __syncthreads();

    f32x4 acc[4][4] = {};
    int cur = 0;
    for (int t = 0; t < 4; ++t) {
        if (t < 3) {
            int kt1 = (t + 1) * 64;
            #pragma unroll
            for (int i = 0; i < 4; ++i) {
                ar[i] = *reinterpret_cast<const bf16x8*>(Agl + (size_t)srow[i] * CC + kt1 + scol);
                br[i] = *reinterpret_cast<const bf16x8*>(Bgl + (size_t)srow[i] * CC + kt1 + scol);
            }
        }
        const __hip_bfloat16* At = &smem[cur * 8192];
        const __hip_bfloat16* Bt = &smem[16384 + cur * 8192];
        #pragma unroll
        for (int kk = 0; kk < 2; ++kk) {
            int col = (kk * 32 + g * 8) ^ ((r16 & 7) << 3);
            bf16x8 a[4], b[4];
            #pragma unroll
            for (int m = 0; m < 4; ++m)
                a[m] = *reinterpret_cast<const bf16x8*>(&At[(wr * 64 + m * 16 + r16) * 64 + col]);
            #pragma unroll
            for (int nn = 0; nn < 4; ++nn)
                b[nn] = *reinterpret_cast<const bf16x8*>(&Bt[(wc * 64 + nn * 16 + r16) * 64 + col]);
            __builtin_amdgcn_s_setprio(1);
            #pragma unroll
            for (int m = 0; m < 4; ++m)
                #pragma unroll
                for (int nn = 0; nn < 4; ++nn)
                    acc[m][nn] = __builtin_amdgcn_mfma_f32_16x16x32_bf16(a[m], b[nn], acc[m][nn], 0, 0, 0);
            __builtin_amdgcn_s_setprio(0);
        }
        if (t < 3) {
            #pragma unroll
            for (int i = 0; i < 4; ++i) {
                *reinterpret_cast<bf16x8*>(&smem[(cur ^ 1) * 8192 + srow[i] * 64 + sswz[i]]) = ar[i];
                *reinterpret_cast<bf16x8*>(&smem[16384 + (cur ^ 1) * 8192 + srow[i] * 64 + sswz[i]]) = br[i];
            }
        }
        __syncthreads();
        cur ^= 1;
    }

    __hip_bfloat16 (*sw)[64][72] = reinterpret_cast<__hip_bfloat16 (*)[64][72]>(smem);

    float bg[4][4];
    #pragma unroll
    for (int m = 0; m < 4; ++m)
        #pragma unroll
        for (int reg = 0; reg < 4; ++reg)
            bg[m][reg] = biasg[o0 + m * 16 + 4 * g + reg];

    size_t head = (size_t)(n * 8 + h);

    if (part < 2) {
        __hip_bfloat16* dst = (part == 0) ? qb : kb;
        #pragma unroll
        for (int nn = 0; nn < 4; ++nn) {
            int l = l0 + nn * 16 + r16;
            float rv[4][4];
            float ss = 0.f;
            #pragma unroll
            for (int m = 0; m < 4; ++m) {
                int j0 = m * 8 + g * 2;
                float cA = cosT[l * 32 + j0],     sA = sinT[l * 32 + j0];
                float cB = cosT[l * 32 + j0 + 1], sB = sinT[l * 32 + j0 + 1];
                float x0 = acc[m][nn][0] + bg[m][0];
                float x1 = acc[m][nn][1] + bg[m][1];
                float x2 = acc[m][nn][2] + bg[m][2];
                float x3 = acc[m][nn][3] + bg[m][3];
                rv[m][0] = x0 * cA - x1 * sA;
                rv[m][1] = x0 * sA + x1 * cA;
                rv[m][2] = x2 * cB - x3 * sB;
                rv[m][3] = x2 * sB + x3 * cB;
                ss += rv[m][0] * rv[m][0] + rv[m][1] * rv[m][1] +
                      rv[m][2] * rv[m][2] + rv[m][3] * rv[m][3];
            }
            ss += __shfl_xor(ss, 16);
            ss += __shfl_xor(ss, 32);
            float inv = 1.0f / (sqrtf(ss) + 1e-8f);
            #pragma unroll
            for (int m = 0; m < 4; ++m)
                #pragma unroll
                for (int reg = 0; reg < 4; ++reg)
                    sw[wid][nn * 16 + r16][m * 16 + 4 * g + reg] =
                        __float2bfloat16(rv[m][reg] * inv);
        }
        #pragma unroll
        for (int it = 0; it < 8; ++it) {
            int idx = lane + it * 64;
            int ll = idx >> 3, ch = idx & 7;
            bf16x8 v = *reinterpret_cast<bf16x8*>(&sw[wid][ll][ch * 8]);
            *reinterpret_cast<bf16x8*>(dst + (head * LL + l0 + ll) * DH + ch * 8) = v;
        }
    } else {
        #pragma unroll
        for (int nn = 0; nn < 4; ++nn)
            #pragma unroll
            for (int m = 0; m < 4; ++m)
                #pragma unroll
                for (int reg = 0; reg < 4; ++reg)
                    sw[wid][m * 16 + 4 * g + reg][nn * 16 + r16] =
                        __float2bfloat16(acc[m][nn][reg] + bg[m][reg]);
        #pragma unroll
        for (int it = 0; it < 8; ++it) {
            int idx = lane + it * 64;
            int dd = idx >> 3, ch = idx & 7;
            bf16x8 v = *reinterpret_cast<bf16x8*>(&sw[wid][dd][ch * 8]);
            *reinterpret_cast<bf16x8*>(vt + (head * DH + dd) * LL + l0 + ch * 8) = v;
        }
    }
}

// ------------- MFMA flash attention: 16 q/wave, 1024 blocks (4/CU), 0-conflict swizzles -------------
// Single-barrier dbuf; swapped QK^T; in-reg P; PV 16x16x16; rowsums via MFMA-ones.
// K tile [l][d] swz col^((l&7)<<3) (16B); V tile [d][l] swz col^((d&15)<<2) (8B granular).
__global__ __launch_bounds__(256) void k_attn_mfma(
    const __hip_bfloat16* __restrict__ qb, const __hip_bfloat16* __restrict__ kb,
    const __hip_bfloat16* __restrict__ vt, const float* __restrict__ sinks,
    __hip_bfloat16* __restrict__ ob) {
    int bid = blockIdx.x;                       // 1024
    int swz = (bid & 7) * 128 + (bid >> 3);     // XCD x owns one n
    int n    = swz >> 7;
    int h    = (swz >> 4) & 7;
    int qblk = swz & 15;
    int tid  = threadIdx.x;
    int wid  = tid >> 6, lane = tid & 63;
    int g = lane >> 4, r16 = lane & 15;

    size_t head = (size_t)(n * 8 + h);
    const __hip_bfloat16* Q = qb + head * (size_t)(LL * DH);
    const __hip_bfloat16* K = kb + head * (size_t)(LL * DH);
    const __hip_bfloat16* V = vt + head * (size_t)(DH * LL);   // [d][l]
    __hip_bfloat16* O = ob + (size_t)n * (LL * 512) + h * 64;  // [l][512]

    int q0 = qblk * 64 + wid * 16;

    __shared__ __hip_bfloat16 kls[2][64][64];
    __shared__ __hip_bfloat16 vls[2][64][64];

    const int cl0 = tid >> 3,         cd0 = (tid & 7) * 8;
    const int cl1 = (tid + 256) >> 3;                          // cl0 + 32
    const int ksw0 = cd0 ^ ((cl0 & 7) << 3);
    const int ksw1 = cd0 ^ ((cl1 & 7) << 3);
    const int vswA0 = cd0       ^ ((cl0 & 15) << 2);
    const int vswB0 = (cd0 + 4) ^ ((cl0 & 15) << 2);
    const int vswA1 = cd0       ^ ((cl1 & 15) << 2);
    const int vswB1 = (cd0 + 4) ^ ((cl1 & 15) << 2);

    bf16x8 qf[2];
    #pragma unroll
    for (int dc = 0; dc < 2; ++dc)
        qf[dc] = *reinterpret_cast<const bf16x8*>(
            Q + (size_t)(q0 + r16) * DH + dc * 32 + g * 8);

    float snk = sinks[h];
    float m = fmaxf(8.0f, snk);
    const float c1 = 8.0f * 1.44269504f;
    const float c0 = -m * 1.44269504f;

    f32x4 oacc[4];
    #pragma unroll
    for (int dn = 0; dn < 4; ++dn)
        oacc[dn] = (f32x4){0.f, 0.f, 0.f, 0.f};
    f32x4 osum = (f32x4){0.f, 0.f, 0.f, 0.f};
    const s16x4 ones = {(short)0x3F80, (short)0x3F80, (short)0x3F80, (short)0x3F80};

    bf16x8 kr0, kr1, vr0, vr1;
    kr0 = *reinterpret_cast<const bf16x8*>(K + (size_t)cl0 * DH + cd0);
    kr1 = *reinterpret_cast<const bf16x8*>(K + (size_t)cl1 * DH + cd0);
    vr0 = *reinterpret_cast<const bf16x8*>(V + (size_t)cl0 * LL + cd0);
    vr1 = *reinterpret_cast<const bf16x8*>(V + (size_t)cl1 * LL + cd0);
    {
        *reinterpret_cast<bf16x8*>(&kls[0][cl0][ksw0]) = kr0;
        *reinterpret_cast<bf16x8*>(&kls[0][cl1][ksw1]) = kr1;
        s16x8 w0 = __builtin_bit_cast(s16x8, vr0);
        s16x8 w1 = __builtin_bit_cast(s16x8, vr1);
        *reinterpret_cast<s16x4*>(&vls[0][cl0][vswA0]) = __builtin_shufflevector(w0, w0, 0, 1, 2, 3);
        *reinterpret_cast<s16x4*>(&vls[0][cl0][vswB0]) = __builtin_shufflevector(w0, w0, 4, 5, 6, 7);
        *reinterpret_cast<s16x4*>(&vls[0][cl1][vswA1]) = __builtin_shufflevector(w1, w1, 0, 1, 2, 3);
        *reinterpret_cast<s16x4*>(&vls[0][cl1][vswB1]) = __builtin_shufflevector(w1, w1, 4, 5, 6, 7);
    }
    __syncthreads();

    int cur = 0;
    for (int t = 0; t < 16; ++t) {
        if (t < 15) {
            int kt1 = t * 64 + 64;
            kr0 = *reinterpret_cast<const bf16x8*>(K + (size_t)(kt1 + cl0) * DH + cd0);
            kr1 = *reinterpret_cast<const bf16x8*>(K + (size_t)(kt1 + cl1) * DH + cd0);
            vr0 = *reinterpret_cast<const bf16x8*>(V + (size_t)cl0 * LL + kt1 + cd0);
            vr1 = *reinterpret_cast<const bf16x8*>(V + (size_t)cl1 * LL + kt1 + cd0);
        }
        f32x4 sacc[4];
        #pragma unroll
        for (int kn = 0; kn < 4; ++kn)
            sacc[kn] = (f32x4){0.f, 0.f, 0.f, 0.f};
        __builtin_amdgcn_s_setprio(1);
        #pragma unroll
        for (int kn = 0; kn < 4; ++kn) {
            #pragma unroll
            for (int dc = 0; dc < 2; ++dc) {
                bf16x8 kf = *reinterpret_cast<const bf16x8*>(
                    &kls[cur][kn * 16 + r16][(dc * 32 + g * 8) ^ ((r16 & 7) << 3)]);
                sacc[kn] = __builtin_amdgcn_mfma_f32_16x16x32_bf16(
                    kf, qf[dc], sacc[kn], 0, 0, 0);
            }
        }
        __builtin_amdgcn_s_setprio(0);
        #pragma unroll
        for (int kn = 0; kn < 4; ++kn) {
            float p0 = exp2f(fmaf(sacc[kn][0], c1, c0));
            float p1 = exp2f(fmaf(sacc[kn][1], c1, c0));
            float p2 = exp2f(fmaf(sacc[kn][2], c1, c0));
            float p3 = exp2f(fmaf(sacc[kn][3], c1, c0));
            bf16x4 pb;
            pb[0] = (__bf16)p0; pb[1] = (__bf16)p1;
            pb[2] = (__bf16)p2; pb[3] = (__bf16)p3;
            s16x4 pa = __builtin_bit_cast(s16x4, pb);
            __builtin_amdgcn_s_setprio(1);
            osum = __builtin_amdgcn_mfma_f32_16x16x16bf16_1k(pa, ones, osum, 0, 0, 0);
            #pragma unroll
            for (int dn = 0; dn < 4; ++dn) {
                s16x4 vb = *reinterpret_cast<const s16x4*>(
                    &vls[cur][dn * 16 + r16][(kn * 16 + g * 4) ^ ((r16 & 15) << 2)]);
                oacc[dn] = __builtin_amdgcn_mfma_f32_16x16x16bf16_1k(pa, vb, oacc[dn], 0, 0, 0);
            }
            __builtin_amdgcn_s_setprio(0);
        }
        if (t < 15) {
            *reinterpret_cast<bf16x8*>(&kls[cur ^ 1][cl0][ksw0]) = kr0;
            *reinterpret_cast<bf16x8*>(&kls[cur ^ 1][cl1][ksw1]) = kr1;
            s16x8 w0 = __builtin_bit_cast(s16x8, vr0);
            s16x8 w1 = __builtin_bit_cast(s16x8, vr1);
            *reinterpret_cast<s16x4*>(&vls[cur ^ 1][cl0][vswA0]) = __builtin_shufflevector(w0, w0, 0, 1, 2, 3);
            *reinterpret_cast<s16x4*>(&vls[cur ^ 1][cl0][vswB0]) = __builtin_shufflevector(w0, w0, 4, 5, 6, 7);
            *reinterpret_cast<s16x4*>(&vls[cur ^ 1][cl1][vswA1]) = __builtin_shufflevector(w1, w1, 0, 1, 2, 3);
            *reinterpret_cast<s16x4*>(&vls[cur ^ 1][cl1][vswB1]) = __builtin_shufflevector(w1, w1, 4, 5, 6, 7);
        }
        __syncthreads();
        cur ^= 1;
    }

    // osum[reg] = rowsum for q = 4g+reg (same layout as oacc rows) -> no shuffles
    float sink_e = exp2f((snk - m) * 1.44269504f);
    #pragma unroll
    for (int reg = 0; reg < 4; ++reg) {
        float invq = 1.0f / (osum[reg] + sink_e);
        #pragma unroll
        for (int dn = 0; dn < 4; ++dn)
            O[(size_t)(q0 + 4 * g + reg) * 512 + dn * 16 + r16] =
                __float2bfloat16(oacc[dn][reg] * invq);
    }
}

// ------------- output projection MFMA, LDS-staged single-barrier dbuf + residual -------------
__global__ __launch_bounds__(256) void k_proj3(const __hip_bfloat16* __restrict__ wpb,
                                               const __hip_bfloat16* __restrict__ ob,
                                               const float* __restrict__ x,
                                               float* __restrict__ out) {
    int lb = blockIdx.x;   // 8
    int cb = blockIdx.y;   // 4
    int n  = blockIdx.z;   // 8
    int tid = threadIdx.x;
    int wid = tid >> 6, lane = tid & 63;
    int wr = wid >> 1, wc = wid & 1;
    int g = lane >> 4, r16 = lane & 15;

    int c0 = cb * 64 + wr * 32;
    int l0 = lb * 128 + wc * 64;

    __shared__ __hip_bfloat16 smem[24576];

    const int arow[2] = {tid >> 3, (tid + 256) >> 3};
    const int brow[4] = {tid >> 3, (tid + 256) >> 3, (tid + 512) >> 3, (tid + 768) >> 3};
    const int scol = (tid & 7) * 8;
    int aswz[2], bswz[4];
    #pragma unroll
    for (int i = 0; i < 2; ++i) aswz[i] = scol ^ ((arow[i] & 7) << 3);
    #pragma unroll
    for (int i = 0; i < 4; ++i) bswz[i] = scol ^ ((brow[i] & 7) << 3);

    const __hip_bfloat16* Agl = wpb + (size_t)(cb * 64) * 512;
    const __hip_bfloat16* Bgl = ob + (size_t)n * (LL * 512) + (size_t)(lb * 128) * 512;

    bf16x8 ar[2], br[4];
    #pragma unroll
    for (int i = 0; i < 2; ++i)
        ar[i] = *reinterpret_cast<const bf16x8*>(Agl + (size_t)arow[i] * 512 + scol);
    #pragma unroll
    for (int i = 0; i < 4; ++i)
        br[i] = *reinterpret_cast<const bf16x8*>(Bgl + (size_t)brow[i] * 512 + scol);
    #pragma unroll
    for (int i = 0; i < 2; ++i)
        *reinterpret_cast<bf16x8*>(&smem[arow[i] * 64 + aswz[i]]) = ar[i];
    #pragma unroll
    for (int i = 0; i < 4; ++i)
        *reinterpret_cast<bf16x8*>(&smem[8192 + brow[i] * 64 + bswz[i]]) = br[i];
    __syncthreads();

    f32x4 acc[2][4] = {};
    int cur = 0;
    for (int t = 0; t < 8; ++t) {
        if (t < 7) {
            int kt1 = (t + 1) * 64;
            #pragma unroll
            for (int i = 0; i < 2; ++i)
                ar[i] = *reinterpret_cast<const bf16x8*>(Agl + (size_t)arow[i] * 512 + kt1 + scol);
            #pragma unroll
            for (int i = 0; i < 4; ++i)
                br[i] = *reinterpret_cast<const bf16x8*>(Bgl + (size_t)brow[i] * 512 + kt1 + scol);
        }
        const __hip_bfloat16* At = &smem[cur * 4096];
        const __hip_bfloat16* Bt = &smem[8192 + cur * 8192];
        #pragma unroll
        for (int kk = 0; kk < 2; ++kk) {
            int col = (kk * 32 + g * 8) ^ ((r16 & 7) << 3);
            bf16x8 a[2], b[4];
            #pragma unroll
            for (int m = 0; m < 2; ++m)
                a[m] = *reinterpret_cast<const bf16x8*>(&At[(wr * 32 + m * 16 + r16) * 64 + col]);
            #pragma unroll
            for (int nn = 0; nn < 4; ++nn)
                b[nn] = *reinterpret_cast<const bf16x8*>(&Bt[(wc * 64 + nn * 16 + r16) * 64 + col]);
            __builtin_amdgcn_s_setprio(1);
            #pragma unroll
            for (int m = 0; m < 2; ++m)
                #pragma unroll
                for (int nn = 0; nn < 4; ++nn)
                    acc[m][nn] = __builtin_amdgcn_mfma_f32_16x16x32_bf16(a[m], b[nn], acc[m][nn], 0, 0, 0);
            __builtin_amdgcn_s_setprio(0);
        }
        if (t < 7) {
            #pragma unroll
            for (int i = 0; i < 2; ++i)
                *reinterpret_cast<bf16x8*>(&smem[(cur ^ 1) * 4096 + arow[i] * 64 + aswz[i]]) = ar[i];
            #pragma unroll
            for (int i = 0; i < 4; ++i)
                *reinterpret_cast<bf16x8*>(&smem[8192 + (cur ^ 1) * 8192 + brow[i] * 64 + bswz[i]]) = br[i];
        }
        __syncthreads();
        cur ^= 1;
    }

    #pragma unroll
    for (int m = 0; m < 2; ++m) {
        #pragma unroll
        for (int reg = 0; reg < 4; ++reg) {
            int c = c0 + m * 16 + 4 * g + reg;
            #pragma unroll
            for (int nn = 0; nn < 4; ++nn) {
                int l = l0 + nn * 16 + r16;
                size_t idx = (size_t)n * (CC * LL) + (size_t)c * LL + l;
                out[idx] = x[idx] + acc[m][nn][reg];
            }
        }
    }
}

extern "C" void kernel_launch(void* const* d_in, const int* in_sizes, int n_in,
                              void* d_out, int out_size, void* d_ws, size_t ws_size,
                              hipStream_t stream) {
    const float* x       = (const float*)d_in[0];
    const float* w       = (const float*)d_in[1];
    const float* igain   = (const float*)d_in[2];
    const float* rgain   = (const float*)d_in[3];
    const float* qkv_w   = (const float*)d_in[4];
    const float* qkv_b   = (const float*)d_in[5];
    const float* mod_w   = (const float*)d_in[6];
    const float* proj_w  = (const float*)d_in[7];
    const float* sinks   = (const float*)d_in[8];
    float* out = (float*)d_out;
    float* ws  = (float*)d_ws;

    float* style = ws + OFF_STYLE;
    float* biasg = ws + OFF_BIAS;
    float* cosT  = ws + OFF_COS;
    float* sinT  = ws + OFF_SIN;
    __hip_bfloat16* wqb = (__hip_bfloat16*)(ws + OFF_WQB);
    __hip_bfloat16* wpb = (__hip_bfloat16*)(ws + OFF_WPB);
    __hip_bfloat16* xmT = (__hip_bfloat16*)(ws + OFF_XMT);
    __hip_bfloat16* qb  = (__hip_bfloat16*)(ws + OFF_Q);
    __hip_bfloat16* kb  = (__hip_bfloat16*)(ws + OFF_K);
    __hip_bfloat16* vt  = (__hip_bfloat16*)(ws + OFF_V);
    __hip_bfloat16* obuf = (__hip_bfloat16*)(ws + OFF_O);

    k_prep<<<544, 256, 0, stream>>>(w, mod_w, style, qkv_w, igain, qkv_b, wqb, biasg,
                                    proj_w, rgain, wpb, cosT, sinT);
    k_xm<<<dim3(16, 4, NN), 256, 0, stream>>>(x, style, xmT);
    k_qkv3<<<dim3(8, 12, NN), 256, 0, stream>>>(wqb, xmT, biasg, cosT, sinT, qb, kb, vt);
    k_attn_mfma<<<1024, 256, 0, stream>>>(qb, kb, vt, sinks, obuf);
    k_proj3<<<dim3(8, 4, NN), 256, 0, stream>>>(wpb, obuf, x, out);
}

// Round 15
// 81.914 us; speedup vs baseline: 1.0403x; 1.0403x over previous
//
#include <hip/hip_runtime.h>
#include <hip/hip_bf16.h>
#include <math.h>

// Problem constants
#define NN 8
#define CC 256
#define LL 1024
#define EE 512
#define HEADS 8
#define DH 64

// Workspace float offsets
#define OFF_STYLE   0u          // 2048
#define OFF_BIAS    2048u       // 1536
#define OFF_COS     3584u       // 32768
#define OFF_SIN     36352u      // 32768
#define OFF_WQB     69120u      // bf16 1536*256 -> 196608 floats
#define OFF_WPB     265728u     // bf16 256*512  -> 65536 floats
#define OFF_XMT     331264u     // bf16 8*1024*256 -> 1048576 floats
#define OFF_Q       1379840u    // bf16 64*1024*64 -> 2097152 floats
#define OFF_K       3476992u
#define OFF_V       5574144u    // bf16 transposed [head][d][l]
#define OFF_O       7671296u    // bf16 [n][l][512] -> 2097152 floats
// total 9768448 floats = 39.1 MB

typedef __bf16 bf16x8 __attribute__((ext_vector_type(8)));
typedef __bf16 bf16x4 __attribute__((ext_vector_type(4)));
typedef short s16x4 __attribute__((ext_vector_type(4)));
typedef short s16x8 __attribute__((ext_vector_type(8)));
typedef float f32x4 __attribute__((ext_vector_type(4)));

// ---------------- fused prep: wq-norm | wp-norm | rope | style in one launch ----------------
__global__ __launch_bounds__(256) void k_prep(
    const float* __restrict__ w, const float* __restrict__ mod_w, float* __restrict__ style,
    const float* __restrict__ qkv_w, const float* __restrict__ gain,
    const float* __restrict__ bias, __hip_bfloat16* __restrict__ wqb, float* __restrict__ biasg,
    const float* __restrict__ proj_w, const float* __restrict__ rgain,
    __hip_bfloat16* __restrict__ wpb,
    float* __restrict__ cosT, float* __restrict__ sinT) {
    int bid = blockIdx.x;
    int t = threadIdx.x;
    int wv = t >> 6, lane = t & 63;
    if (bid < 384) {
        int o = bid * 4 + wv;
        float4 v = *reinterpret_cast<const float4*>(qkv_w + o * CC + lane * 4);
        float s = v.x + v.y + v.z + v.w;
        #pragma unroll
        for (int off = 1; off < 64; off <<= 1) s += __shfl_xor(s, off);
        float mean = s * (1.0f / 256.0f);
        float c0 = v.x - mean, c1 = v.y - mean, c2 = v.z - mean, c3 = v.w - mean;
        float ss = c0 * c0 + c1 * c1 + c2 * c2 + c3 * c3;
        #pragma unroll
        for (int off = 1; off < 64; off <<= 1) ss += __shfl_xor(ss, off);
        float g = gain[o];
        float scale = g / ((sqrtf(ss) + 1e-8f) * 16.0f);
        bf16x4 outv;
        outv[0] = (__bf16)(c0 * scale); outv[1] = (__bf16)(c1 * scale);
        outv[2] = (__bf16)(c2 * scale); outv[3] = (__bf16)(c3 * scale);
        *reinterpret_cast<bf16x4*>((__bf16*)wqb + o * CC + lane * 4) = outv;
        if (lane == 0) biasg[o] = bias[o] * g;
    } else if (bid < 448) {
        int r = (bid - 384) * 4 + wv;
        const float* p = proj_w + r * 512 + lane * 8;
        float4 v0 = *reinterpret_cast<const float4*>(p);
        float4 v1 = *reinterpret_cast<const float4*>(p + 4);
        float s = v0.x + v0.y + v0.z + v0.w + v1.x + v1.y + v1.z + v1.w;
        #pragma unroll
        for (int off = 1; off < 64; off <<= 1) s += __shfl_xor(s, off);
        float mean = s * (1.0f / 512.0f);
        float c[8] = {v0.x - mean, v0.y - mean, v0.z - mean, v0.w - mean,
                      v1.x - mean, v1.y - mean, v1.z - mean, v1.w - mean};
        float ss = 0.f;
        #pragma unroll
        for (int i = 0; i < 8; ++i) ss += c[i] * c[i];
        #pragma unroll
        for (int off = 1; off < 64; off <<= 1) ss += __shfl_xor(ss, off);
        float scale = rgain[r] / ((sqrtf(ss) + 1e-8f) * 22.62741699796952f);
        bf16x8 outv;
        #pragma unroll
        for (int i = 0; i < 8; ++i) outv[i] = (__bf16)(c[i] * scale);
        *reinterpret_cast<bf16x8*>((__bf16*)wpb + r * 512 + lane * 8) = outv;
    } else if (bid < 512) {
        int idx = (bid - 448) * 256 + t;
        int l = idx >> 4, j = idx & 15;
        int hh = l >> 5, ww = l & 31;
        float f = exp2f(-(float)j * 0.8304820238941836f);
        float s1, c1, s2, c2;
        __sincosf((float)hh * f, &s1, &c1);
        __sincosf((float)ww * f, &s2, &c2);
        cosT[l * 32 + j]      = c1;
        sinT[l * 32 + j]      = s1;
        cosT[l * 32 + 16 + j] = c2;
        sinT[l * 32 + 16 + j] = s2;
    } else {
        int b = bid - 512;
        int n = b >> 2, cg = b & 3;
        int c = cg * 64 + lane;
        __shared__ float red[4][64];
        float acc = 0.f;
        #pragma unroll 8
        for (int e = wv * 128; e < wv * 128 + 128; ++e)
            acc += w[n * EE + e] * mod_w[e * CC + c];
        red[wv][lane] = acc;
        __syncthreads();
        if (wv == 0)
            style[n * CC + c] = red[0][lane] + red[1][lane] + red[2][lane] + red[3][lane] + 1.0f;
    }
}

// ------------- prep: xmT[n][l][c] = bf16(x[n][c][l] * style[n][c]) -------------
__global__ __launch_bounds__(256) void k_xm(const float* __restrict__ x,
                                            const float* __restrict__ style,
                                            __hip_bfloat16* __restrict__ xmT) {
    int lb = blockIdx.x;   // 16
    int cb = blockIdx.y;   // 4
    int n  = blockIdx.z;   // 8
    int t = threadIdx.x;
    __shared__ float tile[64][68];
    int r = t >> 2, q = t & 3;
    float st = style[n * CC + cb * 64 + r];
    const float* xp = x + (size_t)n * (CC * LL) + (size_t)(cb * 64 + r) * LL + lb * 64 + q * 16;
    #pragma unroll
    for (int i = 0; i < 4; ++i) {
        float4 v = *reinterpret_cast<const float4*>(xp + i * 4);
        tile[r][q * 16 + i * 4 + 0] = v.x * st;
        tile[r][q * 16 + i * 4 + 1] = v.y * st;
        tile[r][q * 16 + i * 4 + 2] = v.z * st;
        tile[r][q * 16 + i * 4 + 3] = v.w * st;
    }
    __syncthreads();
    __hip_bfloat16 outv[16];
    #pragma unroll
    for (int i = 0; i < 16; ++i)
        outv[i] = __float2bfloat16(tile[q * 16 + i][r]);
    __hip_bfloat16* dst = xmT + (size_t)n * (LL * CC) + (size_t)(lb * 64 + r) * CC + cb * 64 + q * 16;
    *reinterpret_cast<bf16x8*>(dst)     = *reinterpret_cast<bf16x8*>(&outv[0]);
    *reinterpret_cast<bf16x8*>(dst + 8) = *reinterpret_cast<bf16x8*>(&outv[8]);
}

// ------------- QKV MFMA GEMM, LDS-staged, single-barrier dbuf + fused epilogue -------------
// Q rows are pre-scaled by 8*log2(e) so attention's exp2 needs no fma.
__global__ __launch_bounds__(256) void k_qkv3(const __hip_bfloat16* __restrict__ wqb,
                                              const __hip_bfloat16* __restrict__ xmT,
                                              const float* __restrict__ biasg,
                                              const float* __restrict__ cosT,
                                              const float* __restrict__ sinT,
                                              __hip_bfloat16* __restrict__ qb,
                                              __hip_bfloat16* __restrict__ kb,
                                              __hip_bfloat16* __restrict__ vt) {
    int lb = blockIdx.x;   // 8
    int ob = blockIdx.y;   // 12
    int n  = blockIdx.z;   // 8
    int tid = threadIdx.x;
    int wid = tid >> 6, lane = tid & 63;
    int wr = wid >> 1, wc = wid & 1;
    int g = lane >> 4, r16 = lane & 15;

    int o0 = ob * 128 + wr * 64;
    int l0 = lb * 128 + wc * 64;
    int part = o0 >> 9;
    int h = (o0 & 511) >> 6;

    __shared__ __hip_bfloat16 smem[32768];

    const int srow[4] = {tid >> 3, (tid + 256) >> 3, (tid + 512) >> 3, (tid + 768) >> 3};
    const int scol = (tid & 7) * 8;
    int sswz[4];
    #pragma unroll
    for (int i = 0; i < 4; ++i) sswz[i] = scol ^ ((srow[i] & 7) << 3);

    const __hip_bfloat16* Agl = wqb + (size_t)(ob * 128) * CC;
    const __hip_bfloat16* Bgl = xmT + (size_t)n * (LL * CC) + (size_t)(lb * 128) * CC;

    bf16x8 ar[4], br[4];
    #pragma unroll
    for (int i = 0; i < 4; ++i) {
        ar[i] = *reinterpret_cast<const bf16x8*>(Agl + (size_t)srow[i] * CC + scol);
        br[i] = *reinterpret_cast<const bf16x8*>(Bgl + (size_t)srow[i] * CC + scol);
    }
    #pragma unroll
    for (int i = 0; i < 4; ++i) {
        *reinterpret_cast<bf16x8*>(&smem[srow[i] * 64 + sswz[i]]) = ar[i];
        *reinterpret_cast<bf16x8*>(&smem[16384 + srow[i] * 64 + sswz[i]]) = br[i];
    }
    __syncthreads();

    f32x4 acc[4][4] = {};
    int cur = 0;
    for (int t = 0; t < 4; ++t) {
        if (t < 3) {
            int kt1 = (t + 1) * 64;
            #pragma unroll
            for (int i = 0; i < 4; ++i) {
                ar[i] = *reinterpret_cast<const bf16x8*>(Agl + (size_t)srow[i] * CC + kt1 + scol);
                br[i] = *reinterpret_cast<const bf16x8*>(Bgl + (size_t)srow[i] * CC + kt1 + scol);
            }
        }
        const __hip_bfloat16* At = &smem[cur * 8192];
        const __hip_bfloat16* Bt = &smem[16384 + cur * 8192];
        #pragma unroll
        for (int kk = 0; kk < 2; ++kk) {
            int col = (kk * 32 + g * 8) ^ ((r16 & 7) << 3);
            bf16x8 a[4], b[4];
            #pragma unroll
            for (int m = 0; m < 4; ++m)
                a[m] = *reinterpret_cast<const bf16x8*>(&At[(wr * 64 + m * 16 + r16) * 64 + col]);
            #pragma unroll
            for (int nn = 0; nn < 4; ++nn)
                b[nn] = *reinterpret_cast<const bf16x8*>(&Bt[(wc * 64 + nn * 16 + r16) * 64 + col]);
            __builtin_amdgcn_s_setprio(1);
            #pragma unroll
            for (int m = 0; m < 4; ++m)
                #pragma unroll
                for (int nn = 0; nn < 4; ++nn)
                    acc[m][nn] = __builtin_amdgcn_mfma_f32_16x16x32_bf16(a[m], b[nn], acc[m][nn], 0, 0, 0);
            __builtin_amdgcn_s_setprio(0);
        }
        if (t < 3) {
            #pragma unroll
            for (int i = 0; i < 4; ++i) {
                *reinterpret_cast<bf16x8*>(&smem[(cur ^ 1) * 8192 + srow[i] * 64 + sswz[i]]) = ar[i];
                *reinterpret_cast<bf16x8*>(&smem[16384 + (cur ^ 1) * 8192 + srow[i] * 64 + sswz[i]]) = br[i];
            }
        }
        __syncthreads();
        cur ^= 1;
    }

    __hip_bfloat16 (*sw)[64][72] = reinterpret_cast<__hip_bfloat16 (*)[64][72]>(smem);

    float bg[4][4];
    #pragma unroll
    for (int m = 0; m < 4; ++m)
        #pragma unroll
        for (int reg = 0; reg < 4; ++reg)
            bg[m][reg] = biasg[o0 + m * 16 + 4 * g + reg];

    size_t head = (size_t)(n * 8 + h);

    if (part < 2) {
        __hip_bfloat16* dst = (part == 0) ? qb : kb;
        float qscale = (part == 0) ? 11.541560327111707f : 1.0f;  // 8*log2(e) folded into Q
        #pragma unroll
        for (int nn = 0; nn < 4; ++nn) {
            int l = l0 + nn * 16 + r16;
            float rv[4][4];
            float ss = 0.f;
            #pragma unroll
            for (int m = 0; m < 4; ++m) {
                int j0 = m * 8 + g * 2;
                float cA = cosT[l * 32 + j0],     sA = sinT[l * 32 + j0];
                float cB = cosT[l * 32 + j0 + 1], sB = sinT[l * 32 + j0 + 1];
                float x0 = acc[m][nn][0] + bg[m][0];
                float x1 = acc[m][nn][1] + bg[m][1];
                float x2 = acc[m][nn][2] + bg[m][2];
                float x3 = acc[m][nn][3] + bg[m][3];
                rv[m][0] = x0 * cA - x1 * sA;
                rv[m][1] = x0 * sA + x1 * cA;
                rv[m][2] = x2 * cB - x3 * sB;
                rv[m][3] = x2 * sB + x3 * cB;
                ss += rv[m][0] * rv[m][0] + rv[m][1] * rv[m][1] +
                      rv[m][2] * rv[m][2] + rv[m][3] * rv[m][3];
            }
            ss += __shfl_xor(ss, 16);
            ss += __shfl_xor(ss, 32);
            float inv = qscale / (sqrtf(ss) + 1e-8f);
            #pragma unroll
            for (int m = 0; m < 4; ++m)
                #pragma unroll
                for (int reg = 0; reg < 4; ++reg)
                    sw[wid][nn * 16 + r16][m * 16 + 4 * g + reg] =
                        __float2bfloat16(rv[m][reg] * inv);
        }
        #pragma unroll
        for (int it = 0; it < 8; ++it) {
            int idx = lane + it * 64;
            int ll = idx >> 3, ch = idx & 7;
            bf16x8 v = *reinterpret_cast<bf16x8*>(&sw[wid][ll][ch * 8]);
            *reinterpret_cast<bf16x8*>(dst + (head * LL + l0 + ll) * DH + ch * 8) = v;
        }
    } else {
        #pragma unroll
        for (int nn = 0; nn < 4; ++nn)
            #pragma unroll
            for (int m = 0; m < 4; ++m)
                #pragma unroll
                for (int reg = 0; reg < 4; ++reg)
                    sw[wid][m * 16 + 4 * g + reg][nn * 16 + r16] =
                        __float2bfloat16(acc[m][nn][reg] + bg[m][reg]);
        #pragma unroll
        for (int it = 0; it < 8; ++it) {
            int idx = lane + it * 64;
            int dd = idx >> 3, ch = idx & 7;
            bf16x8 v = *reinterpret_cast<bf16x8*>(&sw[wid][dd][ch * 8]);
            *reinterpret_cast<bf16x8*>(vt + (head * DH + dd) * LL + l0 + ch * 8) = v;
        }
    }
}

// ------------- MFMA flash attention: 32 q/wave, KVBLK=128 (2x64 sub-tiles), 1 barrier/tile -------------
// Q pre-scaled by 8*log2e => p = exp2(sacc), no per-score fma. 0-conflict swizzles.
__global__ __launch_bounds__(256) void k_attn_mfma(
    const __hip_bfloat16* __restrict__ qb, const __hip_bfloat16* __restrict__ kb,
    const __hip_bfloat16* __restrict__ vt, const float* __restrict__ sinks,
    __hip_bfloat16* __restrict__ ob) {
    int bid = blockIdx.x;                       // 512
    int swz = (bid & 7) * 64 + (bid >> 3);      // XCD x owns one n
    int n    = swz >> 6;
    int h    = (swz >> 3) & 7;
    int qblk = swz & 7;
    int tid  = threadIdx.x;
    int wid  = tid >> 6, lane = tid & 63;
    int g = lane >> 4, r16 = lane & 15;

    size_t head = (size_t)(n * 8 + h);
    const __hip_bfloat16* Q = qb + head * (size_t)(LL * DH);
    const __hip_bfloat16* K = kb + head * (size_t)(LL * DH);
    const __hip_bfloat16* V = vt + head * (size_t)(DH * LL);   // [d][l]
    __hip_bfloat16* O = ob + (size_t)n * (LL * 512) + h * 64;  // [l][512]

    int q0 = qblk * 128 + wid * 32;

    // KVBLK=128 tiles, double-buffered: K [128][64], V [64][128]
    __shared__ __hip_bfloat16 kls[2][128][64];
    __shared__ __hip_bfloat16 vls[2][64][128];

    // K staging: 1024 chunks (128 rows x 8), 4 per thread
    const int kcl = tid >> 3, kcd = (tid & 7) * 8;
    // V staging: 1024 chunks (64 rows x 16), 4 per thread
    const int vcl = tid >> 4, vcd = (tid & 15) * 8;
    int kswz[4], vswzA[4], vswzB[4];
    #pragma unroll
    for (int i = 0; i < 4; ++i) {
        kswz[i]  = kcd ^ (((kcl + i * 32) & 7) << 3);
        vswzA[i] = vcd ^ (((vcl + i * 16) & 15) << 2);
        vswzB[i] = (vcd + 4) ^ (((vcl + i * 16) & 15) << 2);
    }

    bf16x8 qf[2][2];
    #pragma unroll
    for (int qm = 0; qm < 2; ++qm)
        #pragma unroll
        for (int dc = 0; dc < 2; ++dc)
            qf[qm][dc] = *reinterpret_cast<const bf16x8*>(
                Q + (size_t)(q0 + qm * 16 + r16) * DH + dc * 32 + g * 8);

    float snk = sinks[h];

    f32x4 oacc[2][4];
    #pragma unroll
    for (int qm = 0; qm < 2; ++qm)
        #pragma unroll
        for (int dn = 0; dn < 4; ++dn)
            oacc[qm][dn] = (f32x4){0.f, 0.f, 0.f, 0.f};
    f32x4 osum[2];
    osum[0] = (f32x4){0.f, 0.f, 0.f, 0.f};
    osum[1] = (f32x4){0.f, 0.f, 0.f, 0.f};
    const s16x4 ones = {(short)0x3F80, (short)0x3F80, (short)0x3F80, (short)0x3F80};

    bf16x8 kr[4], vr[4];
    #pragma unroll
    for (int i = 0; i < 4; ++i) {
        kr[i] = *reinterpret_cast<const bf16x8*>(K + (size_t)(kcl + i * 32) * DH + kcd);
        vr[i] = *reinterpret_cast<const bf16x8*>(V + (size_t)(vcl + i * 16) * LL + vcd);
    }
    #pragma unroll
    for (int i = 0; i < 4; ++i) {
        *reinterpret_cast<bf16x8*>(&kls[0][kcl + i * 32][kswz[i]]) = kr[i];
        s16x8 wv8 = __builtin_bit_cast(s16x8, vr[i]);
        *reinterpret_cast<s16x4*>(&vls[0][vcl + i * 16][vswzA[i]]) = __builtin_shufflevector(wv8, wv8, 0, 1, 2, 3);
        *reinterpret_cast<s16x4*>(&vls[0][vcl + i * 16][vswzB[i]]) = __builtin_shufflevector(wv8, wv8, 4, 5, 6, 7);
    }
    __syncthreads();

    int cur = 0;
    for (int t = 0; t < 8; ++t) {
        if (t < 7) {
            int kt1 = (t + 1) * 128;
            #pragma unroll
            for (int i = 0; i < 4; ++i) {
                kr[i] = *reinterpret_cast<const bf16x8*>(K + (size_t)(kt1 + kcl + i * 32) * DH + kcd);
                vr[i] = *reinterpret_cast<const bf16x8*>(V + (size_t)(vcl + i * 16) * LL + kt1 + vcd);
            }
        }
        #pragma unroll
        for (int sub = 0; sub < 2; ++sub) {
            f32x4 sacc[2][4];
            #pragma unroll
            for (int qm = 0; qm < 2; ++qm)
                #pragma unroll
                for (int kn = 0; kn < 4; ++kn)
                    sacc[qm][kn] = (f32x4){0.f, 0.f, 0.f, 0.f};
            __builtin_amdgcn_s_setprio(1);
            #pragma unroll
            for (int kn = 0; kn < 4; ++kn) {
                int krow = sub * 64 + kn * 16 + r16;
                #pragma unroll
                for (int dc = 0; dc < 2; ++dc) {
                    bf16x8 kf = *reinterpret_cast<const bf16x8*>(
                        &kls[cur][krow][(dc * 32 + g * 8) ^ ((r16 & 7) << 3)]);
                    #pragma unroll
                    for (int qm = 0; qm < 2; ++qm)
                        sacc[qm][kn] = __builtin_amdgcn_mfma_f32_16x16x32_bf16(
                            kf, qf[qm][dc], sacc[qm][kn], 0, 0, 0);
                }
            }
            __builtin_amdgcn_s_setprio(0);
            #pragma unroll
            for (int kn = 0; kn < 4; ++kn) {
                s16x4 pa[2];
                #pragma unroll
                for (int qm = 0; qm < 2; ++qm) {
                    // Q pre-scaled: p = exp2(sacc), no fma
                    float p0 = exp2f(sacc[qm][kn][0]);
                    float p1 = exp2f(sacc[qm][kn][1]);
                    float p2 = exp2f(sacc[qm][kn][2]);
                    float p3 = exp2f(sacc[qm][kn][3]);
                    bf16x4 pb;
                    pb[0] = (__bf16)p0; pb[1] = (__bf16)p1;
                    pb[2] = (__bf16)p2; pb[3] = (__bf16)p3;
                    pa[qm] = __builtin_bit_cast(s16x4, pb);
                }
                __builtin_amdgcn_s_setprio(1);
                #pragma unroll
                for (int qm = 0; qm < 2; ++qm)
                    osum[qm] = __builtin_amdgcn_mfma_f32_16x16x16bf16_1k(pa[qm], ones, osum[qm], 0, 0, 0);
                #pragma unroll
                for (int dn = 0; dn < 4; ++dn) {
                    int vcol = sub * 64 + kn * 16 + g * 4;
                    s16x4 vb = *reinterpret_cast<const s16x4*>(
                        &vls[cur][dn * 16 + r16][vcol ^ ((r16 & 15) << 2)]);
                    #pragma unroll
                    for (int qm = 0; qm < 2; ++qm)
                        oacc[qm][dn] = __builtin_amdgcn_mfma_f32_16x16x16bf16_1k(
                            pa[qm], vb, oacc[qm][dn], 0, 0, 0);
                }
                __builtin_amdgcn_s_setprio(0);
            }
        }
        if (t < 7) {
            #pragma unroll
            for (int i = 0; i < 4; ++i) {
                *reinterpret_cast<bf16x8*>(&kls[cur ^ 1][kcl + i * 32][kswz[i]]) = kr[i];
                s16x8 wv8 = __builtin_bit_cast(s16x8, vr[i]);
                *reinterpret_cast<s16x4*>(&vls[cur ^ 1][vcl + i * 16][vswzA[i]]) = __builtin_shufflevector(wv8, wv8, 0, 1, 2, 3);
                *reinterpret_cast<s16x4*>(&vls[cur ^ 1][vcl + i * 16][vswzB[i]]) = __builtin_shufflevector(wv8, wv8, 4, 5, 6, 7);
            }
        }
        __syncthreads();
        cur ^= 1;
    }

    // osum[qm][reg] = rowsum for q = qm*16 + 4g+reg; p unshifted => sink term unshifted
    float sink_e = exp2f(snk * 1.44269504f);
    #pragma unroll
    for (int qm = 0; qm < 2; ++qm) {
        #pragma unroll
        for (int reg = 0; reg < 4; ++reg) {
            float invq = 1.0f / (osum[qm][reg] + sink_e);
            #pragma unroll
            for (int dn = 0; dn < 4; ++dn)
                O[(size_t)(q0 + qm * 16 + 4 * g + reg) * 512 + dn * 16 + r16] =
                    __float2bfloat16(oacc[qm][dn][reg] * invq);
        }
    }
}

// ------------- output projection MFMA, LDS-staged single-barrier dbuf + residual -------------
__global__ __launch_bounds__(256) void k_proj3(const __hip_bfloat16* __restrict__ wpb,
                                               const __hip_bfloat16* __restrict__ ob,
                                               const float* __restrict__ x,
                                               float* __restrict__ out) {
    int lb = blockIdx.x;   // 8
    int cb = blockIdx.y;   // 4
    int n  = blockIdx.z;   // 8
    int tid = threadIdx.x;
    int wid = tid >> 6, lane = tid & 63;
    int wr = wid >> 1, wc = wid & 1;
    int g = lane >> 4, r16 = lane & 15;

    int c0 = cb * 64 + wr * 32;
    int l0 = lb * 128 + wc * 64;

    __shared__ __hip_bfloat16 smem[24576];

    const int arow[2] = {tid >> 3, (tid + 256) >> 3};
    const int brow[4] = {tid >> 3, (tid + 256) >> 3, (tid + 512) >> 3, (tid + 768) >> 3};
    const int scol = (tid & 7) * 8;
    int aswz[2], bswz[4];
    #pragma unroll
    for (int i = 0; i < 2; ++i) aswz[i] = scol ^ ((arow[i] & 7) << 3);
    #pragma unroll
    for (int i = 0; i < 4; ++i) bswz[i] = scol ^ ((brow[i] & 7) << 3);

    const __hip_bfloat16* Agl = wpb + (size_t)(cb * 64) * 512;
    const __hip_bfloat16* Bgl = ob + (size_t)n * (LL * 512) + (size_t)(lb * 128) * 512;

    bf16x8 ar[2], br[4];
    #pragma unroll
    for (int i = 0; i < 2; ++i)
        ar[i] = *reinterpret_cast<const bf16x8*>(Agl + (size_t)arow[i] * 512 + scol);
    #pragma unroll
    for (int i = 0; i < 4; ++i)
        br[i] = *reinterpret_cast<const bf16x8*>(Bgl + (size_t)brow[i] * 512 + scol);
    #pragma unroll
    for (int i = 0; i < 2; ++i)
        *reinterpret_cast<bf16x8*>(&smem[arow[i] * 64 + aswz[i]]) = ar[i];
    #pragma unroll
    for (int i = 0; i < 4; ++i)
        *reinterpret_cast<bf16x8*>(&smem[8192 + brow[i] * 64 + bswz[i]]) = br[i];
    __syncthreads();

    f32x4 acc[2][4] = {};
    int cur = 0;
    for (int t = 0; t < 8; ++t) {
        if (t < 7) {
            int kt1 = (t + 1) * 64;
            #pragma unroll
            for (int i = 0; i < 2; ++i)
                ar[i] = *reinterpret_cast<const bf16x8*>(Agl + (size_t)arow[i] * 512 + kt1 + scol);
            #pragma unroll
            for (int i = 0; i < 4; ++i)
                br[i] = *reinterpret_cast<const bf16x8*>(Bgl + (size_t)brow[i] * 512 + kt1 + scol);
        }
        const __hip_bfloat16* At = &smem[cur * 4096];
        const __hip_bfloat16* Bt = &smem[8192 + cur * 8192];
        #pragma unroll
        for (int kk = 0; kk < 2; ++kk) {
            int col = (kk * 32 + g * 8) ^ ((r16 & 7) << 3);
            bf16x8 a[2], b[4];
            #pragma unroll
            for (int m = 0; m < 2; ++m)
                a[m] = *reinterpret_cast<const bf16x8*>(&At[(wr * 32 + m * 16 + r16) * 64 + col]);
            #pragma unroll
            for (int nn = 0; nn < 4; ++nn)
                b[nn] = *reinterpret_cast<const bf16x8*>(&Bt[(wc * 64 + nn * 16 + r16) * 64 + col]);
            __builtin_amdgcn_s_setprio(1);
            #pragma unroll
            for (int m = 0; m < 2; ++m)
                #pragma unroll
                for (int nn = 0; nn < 4; ++nn)
                    acc[m][nn] = __builtin_amdgcn_mfma_f32_16x16x32_bf16(a[m], b[nn], acc[m][nn], 0, 0, 0);
            __builtin_amdgcn_s_setprio(0);
        }
        if (t < 7) {
            #pragma unroll
            for (int i = 0; i < 2; ++i)
                *reinterpret_cast<bf16x8*>(&smem[(cur ^ 1) * 4096 + arow[i] * 64 + aswz[i]]) = ar[i];
            #pragma unroll
            for (int i = 0; i < 4; ++i)
                *reinterpret_cast<bf16x8*>(&smem[8192 + (cur ^ 1) * 8192 + brow[i] * 64 + bswz[i]]) = br[i];
        }
        __syncthreads();
        cur ^= 1;
    }

    #pragma unroll
    for (int m = 0; m < 2; ++m) {
        #pragma unroll
        for (int reg = 0; reg < 4; ++reg) {
            int c = c0 + m * 16 + 4 * g + reg;
            #pragma unroll
            for (int nn = 0; nn < 4; ++nn) {
                int l = l0 + nn * 16 + r16;
                size_t idx = (size_t)n * (CC * LL) + (size_t)c * LL + l;
                out[idx] = x[idx] + acc[m][nn][reg];
            }
        }
    }
}

extern "C" void kernel_launch(void* const* d_in, const int* in_sizes, int n_in,
                              void* d_out, int out_size, void* d_ws, size_t ws_size,
                              hipStream_t stream) {
    const float* x       = (const float*)d_in[0];
    const float* w       = (const float*)d_in[1];
    const float* igain   = (const float*)d_in[2];
    const float* rgain   = (const float*)d_in[3];
    const float* qkv_w   = (const float*)d_in[4];
    const float* qkv_b   = (const float*)d_in[5];
    const float* mod_w   = (const float*)d_in[6];
    const float* proj_w  = (const float*)d_in[7];
    const float* sinks   = (const float*)d_in[8];
    float* out = (float*)d_out;
    float* ws  = (float*)d_ws;

    float* style = ws + OFF_STYLE;
    float* biasg = ws + OFF_BIAS;
    float* cosT  = ws + OFF_COS;
    float* sinT  = ws + OFF_SIN;
    __hip_bfloat16* wqb = (__hip_bfloat16*)(ws + OFF_WQB);
    __hip_bfloat16* wpb = (__hip_bfloat16*)(ws + OFF_WPB);
    __hip_bfloat16* xmT = (__hip_bfloat16*)(ws + OFF_XMT);
    __hip_bfloat16* qb  = (__hip_bfloat16*)(ws + OFF_Q);
    __hip_bfloat16* kb  = (__hip_bfloat16*)(ws + OFF_K);
    __hip_bfloat16* vt  = (__hip_bfloat16*)(ws + OFF_V);
    __hip_bfloat16* obuf = (__hip_bfloat16*)(ws + OFF_O);

    k_prep<<<544, 256, 0, stream>>>(w, mod_w, style, qkv_w, igain, qkv_b, wqb, biasg,
                                    proj_w, rgain, wpb, cosT, sinT);
    k_xm<<<dim3(16, 4, NN), 256, 0, stream>>>(x, style, xmT);
    k_qkv3<<<dim3(8, 12, NN), 256, 0, stream>>>(wqb, xmT, biasg, cosT, sinT, qb, kb, vt);
    k_attn_mfma<<<512, 256, 0, stream>>>(qb, kb, vt, sinks, obuf);
    k_proj3<<<dim3(8, 4, NN), 256, 0, stream>>>(wpb, obuf, x, out);
}

// Round 18
// 81.527 us; speedup vs baseline: 1.0453x; 1.0047x over previous
//
#include <hip/hip_runtime.h>
#include <hip/hip_bf16.h>
#include <math.h>

// Problem constants
#define NN 8
#define CC 256
#define LL 1024
#define EE 512
#define HEADS 8
#define DH 64

// Workspace float offsets
#define OFF_STYLE   0u          // 2048
#define OFF_BIAS    2048u       // 1536
#define OFF_COS     3584u       // 32768
#define OFF_SIN     36352u      // 32768
#define OFF_WQB     69120u      // bf16 1536*256 -> 196608 floats
#define OFF_WPB     265728u     // bf16 256*512  -> 65536 floats
#define OFF_XMT     331264u     // bf16 8*1024*256 -> 1048576 floats
#define OFF_Q       1379840u    // bf16 64*1024*64 -> 2097152 floats
#define OFF_K       3476992u
#define OFF_V       5574144u    // bf16 transposed [head][d][l]
#define OFF_O       7671296u    // bf16 [n][l][512] -> 2097152 floats
// total 9768448 floats = 39.1 MB

typedef __bf16 bf16x8 __attribute__((ext_vector_type(8)));
typedef __bf16 bf16x4 __attribute__((ext_vector_type(4)));
typedef short s16x4 __attribute__((ext_vector_type(4)));
typedef short s16x8 __attribute__((ext_vector_type(8)));
typedef float f32x4 __attribute__((ext_vector_type(4)));

// ---------------- fused prep: wq-norm | wp-norm | rope | style in one launch ----------------
__global__ __launch_bounds__(256) void k_prep(
    const float* __restrict__ w, const float* __restrict__ mod_w, float* __restrict__ style,
    const float* __restrict__ qkv_w, const float* __restrict__ gain,
    const float* __restrict__ bias, __hip_bfloat16* __restrict__ wqb, float* __restrict__ biasg,
    const float* __restrict__ proj_w, const float* __restrict__ rgain,
    __hip_bfloat16* __restrict__ wpb,
    float* __restrict__ cosT, float* __restrict__ sinT) {
    int bid = blockIdx.x;
    int t = threadIdx.x;
    int wv = t >> 6, lane = t & 63;
    if (bid < 384) {
        int o = bid * 4 + wv;
        float4 v = *reinterpret_cast<const float4*>(qkv_w + o * CC + lane * 4);
        float s = v.x + v.y + v.z + v.w;
        #pragma unroll
        for (int off = 1; off < 64; off <<= 1) s += __shfl_xor(s, off);
        float mean = s * (1.0f / 256.0f);
        float c0 = v.x - mean, c1 = v.y - mean, c2 = v.z - mean, c3 = v.w - mean;
        float ss = c0 * c0 + c1 * c1 + c2 * c2 + c3 * c3;
        #pragma unroll
        for (int off = 1; off < 64; off <<= 1) ss += __shfl_xor(ss, off);
        float g = gain[o];
        float scale = g / ((sqrtf(ss) + 1e-8f) * 16.0f);
        bf16x4 outv;
        outv[0] = (__bf16)(c0 * scale); outv[1] = (__bf16)(c1 * scale);
        outv[2] = (__bf16)(c2 * scale); outv[3] = (__bf16)(c3 * scale);
        *reinterpret_cast<bf16x4*>((__bf16*)wqb + o * CC + lane * 4) = outv;
        if (lane == 0) biasg[o] = bias[o] * g;
    } else if (bid < 448) {
        int r = (bid - 384) * 4 + wv;
        const float* p = proj_w + r * 512 + lane * 8;
        float4 v0 = *reinterpret_cast<const float4*>(p);
        float4 v1 = *reinterpret_cast<const float4*>(p + 4);
        float s = v0.x + v0.y + v0.z + v0.w + v1.x + v1.y + v1.z + v1.w;
        #pragma unroll
        for (int off = 1; off < 64; off <<= 1) s += __shfl_xor(s, off);
        float mean = s * (1.0f / 512.0f);
        float c[8] = {v0.x - mean, v0.y - mean, v0.z - mean, v0.w - mean,
                      v1.x - mean, v1.y - mean, v1.z - mean, v1.w - mean};
        float ss = 0.f;
        #pragma unroll
        for (int i = 0; i < 8; ++i) ss += c[i] * c[i];
        #pragma unroll
        for (int off = 1; off < 64; off <<= 1) ss += __shfl_xor(ss, off);
        float scale = rgain[r] / ((sqrtf(ss) + 1e-8f) * 22.62741699796952f);
        bf16x8 outv;
        #pragma unroll
        for (int i = 0; i < 8; ++i) outv[i] = (__bf16)(c[i] * scale);
        *reinterpret_cast<bf16x8*>((__bf16*)wpb + r * 512 + lane * 8) = outv;
    } else if (bid < 512) {
        int idx = (bid - 448) * 256 + t;
        int l = idx >> 4, j = idx & 15;
        int hh = l >> 5, ww = l & 31;
        float f = exp2f(-(float)j * 0.8304820238941836f);
        float s1, c1, s2, c2;
        __sincosf((float)hh * f, &s1, &c1);
        __sincosf((float)ww * f, &s2, &c2);
        cosT[l * 32 + j]      = c1;
        sinT[l * 32 + j]      = s1;
        cosT[l * 32 + 16 + j] = c2;
        sinT[l * 32 + 16 + j] = s2;
    } else {
        int b = bid - 512;
        int n = b >> 2, cg = b & 3;
        int c = cg * 64 + lane;
        __shared__ float red[4][64];
        float acc = 0.f;
        #pragma unroll 8
        for (int e = wv * 128; e < wv * 128 + 128; ++e)
            acc += w[n * EE + e] * mod_w[e * CC + c];
        red[wv][lane] = acc;
        __syncthreads();
        if (wv == 0)
            style[n * CC + c] = red[0][lane] + red[1][lane] + red[2][lane] + red[3][lane] + 1.0f;
    }
}

// ------------- prep: xmT[n][l][c] = bf16(x[n][c][l] * style[n][c]) -------------
__global__ __launch_bounds__(256) void k_xm(const float* __restrict__ x,
                                            const float* __restrict__ style,
                                            __hip_bfloat16* __restrict__ xmT) {
    int lb = blockIdx.x;   // 16
    int cb = blockIdx.y;   // 4
    int n  = blockIdx.z;   // 8
    int t = threadIdx.x;
    __shared__ float tile[64][68];
    int r = t >> 2, q = t & 3;
    float st = style[n * CC + cb * 64 + r];
    const float* xp = x + (size_t)n * (CC * LL) + (size_t)(cb * 64 + r) * LL + lb * 64 + q * 16;
    #pragma unroll
    for (int i = 0; i < 4; ++i) {
        float4 v = *reinterpret_cast<const float4*>(xp + i * 4);
        tile[r][q * 16 + i * 4 + 0] = v.x * st;
        tile[r][q * 16 + i * 4 + 1] = v.y * st;
        tile[r][q * 16 + i * 4 + 2] = v.z * st;
        tile[r][q * 16 + i * 4 + 3] = v.w * st;
    }
    __syncthreads();
    __hip_bfloat16 outv[16];
    #pragma unroll
    for (int i = 0; i < 16; ++i)
        outv[i] = __float2bfloat16(tile[q * 16 + i][r]);
    __hip_bfloat16* dst = xmT + (size_t)n * (LL * CC) + (size_t)(lb * 64 + r) * CC + cb * 64 + q * 16;
    *reinterpret_cast<bf16x8*>(dst)     = *reinterpret_cast<bf16x8*>(&outv[0]);
    *reinterpret_cast<bf16x8*>(dst + 8) = *reinterpret_cast<bf16x8*>(&outv[8]);
}

// ------------- QKV MFMA GEMM, LDS-staged, single-barrier dbuf + fused epilogue -------------
// Q rows are pre-scaled by 8*log2(e) so attention's exp2 needs no fma.
__global__ __launch_bounds__(256) void k_qkv3(const __hip_bfloat16* __restrict__ wqb,
                                              const __hip_bfloat16* __restrict__ xmT,
                                              const float* __restrict__ biasg,
                                              const float* __restrict__ cosT,
                                              const float* __restrict__ sinT,
                                              __hip_bfloat16* __restrict__ qb,
                                              __hip_bfloat16* __restrict__ kb,
                                              __hip_bfloat16* __restrict__ vt) {
    int lb = blockIdx.x;   // 8
    int ob = blockIdx.y;   // 12
    int n  = blockIdx.z;   // 8
    int tid = threadIdx.x;
    int wid = tid >> 6, lane = tid & 63;
    int wr = wid >> 1, wc = wid & 1;
    int g = lane >> 4, r16 = lane & 15;

    int o0 = ob * 128 + wr * 64;
    int l0 = lb * 128 + wc * 64;
    int part = o0 >> 9;
    int h = (o0 & 511) >> 6;

    __shared__ __hip_bfloat16 smem[32768];

    const int srow[4] = {tid >> 3, (tid + 256) >> 3, (tid + 512) >> 3, (tid + 768) >> 3};
    const int scol = (tid & 7) * 8;
    int sswz[4];
    #pragma unroll
    for (int i = 0; i < 4; ++i) sswz[i] = scol ^ ((srow[i] & 7) << 3);

    const __hip_bfloat16* Agl = wqb + (size_t)(ob * 128) * CC;
    const __hip_bfloat16* Bgl = xmT + (size_t)n * (LL * CC) + (size_t)(lb * 128) * CC;

    bf16x8 ar[4], br[4];
    #pragma unroll
    for (int i = 0; i < 4; ++i) {
        ar[i] = *reinterpret_cast<const bf16x8*>(Agl + (size_t)srow[i] * CC + scol);
        br[i] = *reinterpret_cast<const bf16x8*>(Bgl + (size_t)srow[i] * CC + scol);
    }
    #pragma unroll
    for (int i = 0; i < 4; ++i) {
        *reinterpret_cast<bf16x8*>(&smem[srow[i] * 64 + sswz[i]]) = ar[i];
        *reinterpret_cast<bf16x8*>(&smem[16384 + srow[i] * 64 + sswz[i]]) = br[i];
    }
    __syncthreads();

    f32x4 acc[4][4] = {};
    int cur = 0;
    for (int t = 0; t < 4; ++t) {
        if (t < 3) {
            int kt1 = (t + 1) * 64;
            #pragma unroll
            for (int i = 0; i < 4; ++i) {
                ar[i] = *reinterpret_cast<const bf16x8*>(Agl + (size_t)srow[i] * CC + kt1 + scol);
                br[i] = *reinterpret_cast<const bf16x8*>(Bgl + (size_t)srow[i] * CC + kt1 + scol);
            }
        }
        const __hip_bfloat16* At = &smem[cur * 8192];
        const __hip_bfloat16* Bt = &smem[16384 + cur * 8192];
        #pragma unroll
        for (int kk = 0; kk < 2; ++kk) {
            int col = (kk * 32 + g * 8) ^ ((r16 & 7) << 3);
            bf16x8 a[4], b[4];
            #pragma unroll
            for (int m = 0; m < 4; ++m)
                a[m] = *reinterpret_cast<const bf16x8*>(&At[(wr * 64 + m * 16 + r16) * 64 + col]);
            #pragma unroll
            for (int nn = 0; nn < 4; ++nn)
                b[nn] = *reinterpret_cast<const bf16x8*>(&Bt[(wc * 64 + nn * 16 + r16) * 64 + col]);
            __builtin_amdgcn_s_setprio(1);
            #pragma unroll
            for (int m = 0; m < 4; ++m)
                #pragma unroll
                for (int nn = 0; nn < 4; ++nn)
                    acc[m][nn] = __builtin_amdgcn_mfma_f32_16x16x32_bf16(a[m], b[nn], acc[m][nn], 0, 0, 0);
            __builtin_amdgcn_s_setprio(0);
        }
        if (t < 3) {
            #pragma unroll
            for (int i = 0; i < 4; ++i) {
                *reinterpret_cast<bf16x8*>(&smem[(cur ^ 1) * 8192 + srow[i] * 64 + sswz[i]]) = ar[i];
                *reinterpret_cast<bf16x8*>(&smem[16384 + (cur ^ 1) * 8192 + srow[i] * 64 + sswz[i]]) = br[i];
            }
        }
        __syncthreads();
        cur ^= 1;
    }

    __hip_bfloat16 (*sw)[64][72] = reinterpret_cast<__hip_bfloat16 (*)[64][72]>(smem);

    float bg[4][4];
    #pragma unroll
    for (int m = 0; m < 4; ++m)
        #pragma unroll
        for (int reg = 0; reg < 4; ++reg)
            bg[m][reg] = biasg[o0 + m * 16 + 4 * g + reg];

    size_t head = (size_t)(n * 8 + h);

    if (part < 2) {
        __hip_bfloat16* dst = (part == 0) ? qb : kb;
        float qscale = (part == 0) ? 11.541560327111707f : 1.0f;  // 8*log2(e) folded into Q
        #pragma unroll
        for (int nn = 0; nn < 4; ++nn) {
            int l = l0 + nn * 16 + r16;
            float rv[4][4];
            float ss = 0.f;
            #pragma unroll
            for (int m = 0; m < 4; ++m) {
                int j0 = m * 8 + g * 2;
                float cA = cosT[l * 32 + j0],     sA = sinT[l * 32 + j0];
                float cB = cosT[l * 32 + j0 + 1], sB = sinT[l * 32 + j0 + 1];
                float x0 = acc[m][nn][0] + bg[m][0];
                float x1 = acc[m][nn][1] + bg[m][1];
                float x2 = acc[m][nn][2] + bg[m][2];
                float x3 = acc[m][nn][3] + bg[m][3];
                rv[m][0] = x0 * cA - x1 * sA;
                rv[m][1] = x0 * sA + x1 * cA;
                rv[m][2] = x2 * cB - x3 * sB;
                rv[m][3] = x2 * sB + x3 * cB;
                ss += rv[m][0] * rv[m][0] + rv[m][1] * rv[m][1] +
                      rv[m][2] * rv[m][2] + rv[m][3] * rv[m][3];
            }
            ss += __shfl_xor(ss, 16);
            ss += __shfl_xor(ss, 32);
            float inv = qscale / (sqrtf(ss) + 1e-8f);
            #pragma unroll
            for (int m = 0; m < 4; ++m)
                #pragma unroll
                for (int reg = 0; reg < 4; ++reg)
                    sw[wid][nn * 16 + r16][m * 16 + 4 * g + reg] =
                        __float2bfloat16(rv[m][reg] * inv);
        }
        #pragma unroll
        for (int it = 0; it < 8; ++it) {
            int idx = lane + it * 64;
            int ll = idx >> 3, ch = idx & 7;
            bf16x8 v = *reinterpret_cast<bf16x8*>(&sw[wid][ll][ch * 8]);
            *reinterpret_cast<bf16x8*>(dst + (head * LL + l0 + ll) * DH + ch * 8) = v;
        }
    } else {
        #pragma unroll
        for (int nn = 0; nn < 4; ++nn)
            #pragma unroll
            for (int m = 0; m < 4; ++m)
                #pragma unroll
                for (int reg = 0; reg < 4; ++reg)
                    sw[wid][m * 16 + 4 * g + reg][nn * 16 + r16] =
                        __float2bfloat16(acc[m][nn][reg] + bg[m][reg]);
        #pragma unroll
        for (int it = 0; it < 8; ++it) {
            int idx = lane + it * 64;
            int dd = idx >> 3, ch = idx & 7;
            bf16x8 v = *reinterpret_cast<bf16x8*>(&sw[wid][dd][ch * 8]);
            *reinterpret_cast<bf16x8*>(vt + (head * DH + dd) * LL + l0 + ch * 8) = v;
        }
    }
}

// ------------- MFMA flash attention: 32 q/wave, KVBLK=128, QK-hoisted phase split -------------
// Per tile: QK(sub0)+QK(sub1) issued back-to-back, THEN exp/PV(sub0), exp/PV(sub1):
// exp(sub0) issues while QK(sub1) MFMAs execute -> hides MFMA-result latency.
__global__ __launch_bounds__(256) void k_attn_mfma(
    const __hip_bfloat16* __restrict__ qb, const __hip_bfloat16* __restrict__ kb,
    const __hip_bfloat16* __restrict__ vt, const float* __restrict__ sinks,
    __hip_bfloat16* __restrict__ ob) {
    int bid = blockIdx.x;                       // 512
    int swz = (bid & 7) * 64 + (bid >> 3);      // XCD x owns one n
    int n    = swz >> 6;
    int h    = (swz >> 3) & 7;
    int qblk = swz & 7;
    int tid  = threadIdx.x;
    int wid  = tid >> 6, lane = tid & 63;
    int g = lane >> 4, r16 = lane & 15;

    size_t head = (size_t)(n * 8 + h);
    const __hip_bfloat16* Q = qb + head * (size_t)(LL * DH);
    const __hip_bfloat16* K = kb + head * (size_t)(LL * DH);
    const __hip_bfloat16* V = vt + head * (size_t)(DH * LL);   // [d][l]
    __hip_bfloat16* O = ob + (size_t)n * (LL * 512) + h * 64;  // [l][512]

    int q0 = qblk * 128 + wid * 32;

    // KVBLK=128 tiles, double-buffered: K [128][64], V [64][128]
    __shared__ __hip_bfloat16 kls[2][128][64];
    __shared__ __hip_bfloat16 vls[2][64][128];

    const int kcl = tid >> 3, kcd = (tid & 7) * 8;
    const int vcl = tid >> 4, vcd = (tid & 15) * 8;
    int kswz[4], vswzA[4], vswzB[4];
    #pragma unroll
    for (int i = 0; i < 4; ++i) {
        kswz[i]  = kcd ^ (((kcl + i * 32) & 7) << 3);
        vswzA[i] = vcd ^ (((vcl + i * 16) & 15) << 2);
        vswzB[i] = (vcd + 4) ^ (((vcl + i * 16) & 15) << 2);
    }

    bf16x8 qf[2][2];
    #pragma unroll
    for (int qm = 0; qm < 2; ++qm)
        #pragma unroll
        for (int dc = 0; dc < 2; ++dc)
            qf[qm][dc] = *reinterpret_cast<const bf16x8*>(
                Q + (size_t)(q0 + qm * 16 + r16) * DH + dc * 32 + g * 8);

    float snk = sinks[h];

    f32x4 oacc[2][4];
    #pragma unroll
    for (int qm = 0; qm < 2; ++qm)
        #pragma unroll
        for (int dn = 0; dn < 4; ++dn)
            oacc[qm][dn] = (f32x4){0.f, 0.f, 0.f, 0.f};
    f32x4 osum[2];
    osum[0] = (f32x4){0.f, 0.f, 0.f, 0.f};
    osum[1] = (f32x4){0.f, 0.f, 0.f, 0.f};
    const s16x4 ones = {(short)0x3F80, (short)0x3F80, (short)0x3F80, (short)0x3F80};

    bf16x8 kr[4], vr[4];
    #pragma unroll
    for (int i = 0; i < 4; ++i) {
        kr[i] = *reinterpret_cast<const bf16x8*>(K + (size_t)(kcl + i * 32) * DH + kcd);
        vr[i] = *reinterpret_cast<const bf16x8*>(V + (size_t)(vcl + i * 16) * LL + vcd);
    }
    #pragma unroll
    for (int i = 0; i < 4; ++i) {
        *reinterpret_cast<bf16x8*>(&kls[0][kcl + i * 32][kswz[i]]) = kr[i];
        s16x8 wv8 = __builtin_bit_cast(s16x8, vr[i]);
        *reinterpret_cast<s16x4*>(&vls[0][vcl + i * 16][vswzA[i]]) = __builtin_shufflevector(wv8, wv8, 0, 1, 2, 3);
        *reinterpret_cast<s16x4*>(&vls[0][vcl + i * 16][vswzB[i]]) = __builtin_shufflevector(wv8, wv8, 4, 5, 6, 7);
    }
    __syncthreads();

    int cur = 0;
    for (int t = 0; t < 8; ++t) {
        if (t < 7) {
            int kt1 = (t + 1) * 128;
            #pragma unroll
            for (int i = 0; i < 4; ++i) {
                kr[i] = *reinterpret_cast<const bf16x8*>(K + (size_t)(kt1 + kcl + i * 32) * DH + kcd);
                vr[i] = *reinterpret_cast<const bf16x8*>(V + (size_t)(vcl + i * 16) * LL + kt1 + vcd);
            }
        }
        // ---- phase 1: QK^T for BOTH 64-kv sub-tiles (back-to-back MFMA issue) ----
        f32x4 sacc[2][2][4];   // [sub][qm][kn]
        #pragma unroll
        for (int sub = 0; sub < 2; ++sub)
            #pragma unroll
            for (int qm = 0; qm < 2; ++qm)
                #pragma unroll
                for (int kn = 0; kn < 4; ++kn)
                    sacc[sub][qm][kn] = (f32x4){0.f, 0.f, 0.f, 0.f};
        __builtin_amdgcn_s_setprio(1);
        #pragma unroll
        for (int sub = 0; sub < 2; ++sub) {
            #pragma unroll
            for (int kn = 0; kn < 4; ++kn) {
                int krow = sub * 64 + kn * 16 + r16;
                #pragma unroll
                for (int dc = 0; dc < 2; ++dc) {
                    bf16x8 kf = *reinterpret_cast<const bf16x8*>(
                        &kls[cur][krow][(dc * 32 + g * 8) ^ ((r16 & 7) << 3)]);
                    #pragma unroll
                    for (int qm = 0; qm < 2; ++qm)
                        sacc[sub][qm][kn] = __builtin_amdgcn_mfma_f32_16x16x32_bf16(
                            kf, qf[qm][dc], sacc[sub][qm][kn], 0, 0, 0);
                }
            }
        }
        __builtin_amdgcn_s_setprio(0);
        // ---- phase 2: exp + PV per sub (exp(sub0) overlaps QK(sub1) execution) ----
        #pragma unroll
        for (int sub = 0; sub < 2; ++sub) {
            #pragma unroll
            for (int kn = 0; kn < 4; ++kn) {
                s16x4 pa[2];
                #pragma unroll
                for (int qm = 0; qm < 2; ++qm) {
                    float p0 = exp2f(sacc[sub][qm][kn][0]);
                    float p1 = exp2f(sacc[sub][qm][kn][1]);
                    float p2 = exp2f(sacc[sub][qm][kn][2]);
                    float p3 = exp2f(sacc[sub][qm][kn][3]);
                    bf16x4 pb;
                    pb[0] = (__bf16)p0; pb[1] = (__bf16)p1;
                    pb[2] = (__bf16)p2; pb[3] = (__bf16)p3;
                    pa[qm] = __builtin_bit_cast(s16x4, pb);
                }
                __builtin_amdgcn_s_setprio(1);
                #pragma unroll
                for (int qm = 0; qm < 2; ++qm)
                    osum[qm] = __builtin_amdgcn_mfma_f32_16x16x16bf16_1k(pa[qm], ones, osum[qm], 0, 0, 0);
                #pragma unroll
                for (int dn = 0; dn < 4; ++dn) {
                    int vcol = sub * 64 + kn * 16 + g * 4;
                    s16x4 vb = *reinterpret_cast<const s16x4*>(
                        &vls[cur][dn * 16 + r16][vcol ^ ((r16 & 15) << 2)]);
                    #pragma unroll
                    for (int qm = 0; qm < 2; ++qm)
                        oacc[qm][dn] = __builtin_amdgcn_mfma_f32_16x16x16bf16_1k(
                            pa[qm], vb, oacc[qm][dn], 0, 0, 0);
                }
                __builtin_amdgcn_s_setprio(0);
            }
        }
        if (t < 7) {
            #pragma unroll
            for (int i = 0; i < 4; ++i) {
                *reinterpret_cast<bf16x8*>(&kls[cur ^ 1][kcl + i * 32][kswz[i]]) = kr[i];
                s16x8 wv8 = __builtin_bit_cast(s16x8, vr[i]);
                *reinterpret_cast<s16x4*>(&vls[cur ^ 1][vcl + i * 16][vswzA[i]]) = __builtin_shufflevector(wv8, wv8, 0, 1, 2, 3);
                *reinterpret_cast<s16x4*>(&vls[cur ^ 1][vcl + i * 16][vswzB[i]]) = __builtin_shufflevector(wv8, wv8, 4, 5, 6, 7);
            }
        }
        __syncthreads();
        cur ^= 1;
    }

    // osum[qm][reg] = rowsum for q = qm*16 + 4g+reg; p unshifted => sink term unshifted
    float sink_e = exp2f(snk * 1.44269504f);
    #pragma unroll
    for (int qm = 0; qm < 2; ++qm) {
        #pragma unroll
        for (int reg = 0; reg < 4; ++reg) {
            float invq = 1.0f / (osum[qm][reg] + sink_e);
            #pragma unroll
            for (int dn = 0; dn < 4; ++dn)
                O[(size_t)(q0 + qm * 16 + 4 * g + reg) * 512 + dn * 16 + r16] =
                    __float2bfloat16(oacc[qm][dn][reg] * invq);
        }
    }
}

// ------------- output projection MFMA, LDS-staged single-barrier dbuf + residual -------------
__global__ __launch_bounds__(256) void k_proj3(const __hip_bfloat16* __restrict__ wpb,
                                               const __hip_bfloat16* __restrict__ ob,
                                               const float* __restrict__ x,
                                               float* __restrict__ out) {
    int lb = blockIdx.x;   // 8
    int cb = blockIdx.y;   // 4
    int n  = blockIdx.z;   // 8
    int tid = threadIdx.x;
    int wid = tid >> 6, lane = tid & 63;
    int wr = wid >> 1, wc = wid & 1;
    int g = lane >> 4, r16 = lane & 15;

    int c0 = cb * 64 + wr * 32;
    int l0 = lb * 128 + wc * 64;

    __shared__ __hip_bfloat16 smem[24576];

    const int arow[2] = {tid >> 3, (tid + 256) >> 3};
    const int brow[4] = {tid >> 3, (tid + 256) >> 3, (tid + 512) >> 3, (tid + 768) >> 3};
    const int scol = (tid & 7) * 8;
    int aswz[2], bswz[4];
    #pragma unroll
    for (int i = 0; i < 2; ++i) aswz[i] = scol ^ ((arow[i] & 7) << 3);
    #pragma unroll
    for (int i = 0; i < 4; ++i) bswz[i] = scol ^ ((brow[i] & 7) << 3);

    const __hip_bfloat16* Agl = wpb + (size_t)(cb * 64) * 512;
    const __hip_bfloat16* Bgl = ob + (size_t)n * (LL * 512) + (size_t)(lb * 128) * 512;

    bf16x8 ar[2], br[4];
    #pragma unroll
    for (int i = 0; i < 2; ++i)
        ar[i] = *reinterpret_cast<const bf16x8*>(Agl + (size_t)arow[i] * 512 + scol);
    #pragma unroll
    for (int i = 0; i < 4; ++i)
        br[i] = *reinterpret_cast<const bf16x8*>(Bgl + (size_t)brow[i] * 512 + scol);
    #pragma unroll
    for (int i = 0; i < 2; ++i)
        *reinterpret_cast<bf16x8*>(&smem[arow[i] * 64 + aswz[i]]) = ar[i];
    #pragma unroll
    for (int i = 0; i < 4; ++i)
        *reinterpret_cast<bf16x8*>(&smem[8192 + brow[i] * 64 + bswz[i]]) = br[i];
    __syncthreads();

    f32x4 acc[2][4] = {};
    int cur = 0;
    for (int t = 0; t < 8; ++t) {
        if (t < 7) {
            int kt1 = (t + 1) * 64;
            #pragma unroll
            for (int i = 0; i < 2; ++i)
                ar[i] = *reinterpret_cast<const bf16x8*>(Agl + (size_t)arow[i] * 512 + kt1 + scol);
            #pragma unroll
            for (int i = 0; i < 4; ++i)
                br[i] = *reinterpret_cast<const bf16x8*>(Bgl + (size_t)brow[i] * 512 + kt1 + scol);
        }
        const __hip_bfloat16* At = &smem[cur * 4096];
        const __hip_bfloat16* Bt = &smem[8192 + cur * 8192];
        #pragma unroll
        for (int kk = 0; kk < 2; ++kk) {
            int col = (kk * 32 + g * 8) ^ ((r16 & 7) << 3);
            bf16x8 a[2], b[4];
            #pragma unroll
            for (int m = 0; m < 2; ++m)
                a[m] = *reinterpret_cast<const bf16x8*>(&At[(wr * 32 + m * 16 + r16) * 64 + col]);
            #pragma unroll
            for (int nn = 0; nn < 4; ++nn)
                b[nn] = *reinterpret_cast<const bf16x8*>(&Bt[(wc * 64 + nn * 16 + r16) * 64 + col]);
            __builtin_amdgcn_s_setprio(1);
            #pragma unroll
            for (int m = 0; m < 2; ++m)
                #pragma unroll
                for (int nn = 0; nn < 4; ++nn)
                    acc[m][nn] = __builtin_amdgcn_mfma_f32_16x16x32_bf16(a[m], b[nn], acc[m][nn], 0, 0, 0);
            __builtin_amdgcn_s_setprio(0);
        }
        if (t < 7) {
            #pragma unroll
            for (int i = 0; i < 2; ++i)
                *reinterpret_cast<bf16x8*>(&smem[(cur ^ 1) * 4096 + arow[i] * 64 + aswz[i]]) = ar[i];
            #pragma unroll
            for (int i = 0; i < 4; ++i)
                *reinterpret_cast<bf16x8*>(&smem[8192 + (cur ^ 1) * 8192 + brow[i] * 64 + bswz[i]]) = br[i];
        }
        __syncthreads();
        cur ^= 1;
    }

    #pragma unroll
    for (int m = 0; m < 2; ++m) {
        #pragma unroll
        for (int reg = 0; reg < 4; ++reg) {
            int c = c0 + m * 16 + 4 * g + reg;
            #pragma unroll
            for (int nn = 0; nn < 4; ++nn) {
                int l = l0 + nn * 16 + r16;
                size_t idx = (size_t)n * (CC * LL) + (size_t)c * LL + l;
                out[idx] = x[idx] + acc[m][nn][reg];
            }
        }
    }
}

extern "C" void kernel_launch(void* const* d_in, const int* in_sizes, int n_in,
                              void* d_out, int out_size, void* d_ws, size_t ws_size,
                              hipStream_t stream) {
    const float* x       = (const float*)d_in[0];
    const float* w       = (const float*)d_in[1];
    const float* igain   = (const float*)d_in[2];
    const float* rgain   = (const float*)d_in[3];
    const float* qkv_w   = (const float*)d_in[4];
    const float* qkv_b   = (const float*)d_in[5];
    const float* mod_w   = (const float*)d_in[6];
    const float* proj_w  = (const float*)d_in[7];
    const float* sinks   = (const float*)d_in[8];
    float* out = (float*)d_out;
    float* ws  = (float*)d_ws;

    float* style = ws + OFF_STYLE;
    float* biasg = ws + OFF_BIAS;
    float* cosT  = ws + OFF_COS;
    float* sinT  = ws + OFF_SIN;
    __hip_bfloat16* wqb = (__hip_bfloat16*)(ws + OFF_WQB);
    __hip_bfloat16* wpb = (__hip_bfloat16*)(ws + OFF_WPB);
    __hip_bfloat16* xmT = (__hip_bfloat16*)(ws + OFF_XMT);
    __hip_bfloat16* qb  = (__hip_bfloat16*)(ws + OFF_Q);
    __hip_bfloat16* kb  = (__hip_bfloat16*)(ws + OFF_K);
    __hip_bfloat16* vt  = (__hip_bfloat16*)(ws + OFF_V);
    __hip_bfloat16* obuf = (__hip_bfloat16*)(ws + OFF_O);

    k_prep<<<544, 256, 0, stream>>>(w, mod_w, style, qkv_w, igain, qkv_b, wqb, biasg,
                                    proj_w, rgain, wpb, cosT, sinT);
    k_xm<<<dim3(16, 4, NN), 256, 0, stream>>>(x, style, xmT);
    k_qkv3<<<dim3(8, 12, NN), 256, 0, stream>>>(wqb, xmT, biasg, cosT, sinT, qb, kb, vt);
    k_attn_mfma<<<512, 256, 0, stream>>>(qb, kb, vt, sinks, obuf);
    k_proj3<<<dim3(8, 4, NN), 256, 0, stream>>>(wpb, obuf, x, out);
}

// Round 20
// 81.042 us; speedup vs baseline: 1.0515x; 1.0060x over previous
//
#include <hip/hip_runtime.h>
#include <hip/hip_bf16.h>
#include <math.h>

// Problem constants
#define NN 8
#define CC 256
#define LL 1024
#define EE 512
#define HEADS 8
#define DH 64

// Workspace float offsets
#define OFF_STYLE   0u          // 2048
#define OFF_BIAS    2048u       // 1536
#define OFF_COS     3584u       // 32768
#define OFF_SIN     36352u      // 32768
#define OFF_WQB     69120u      // bf16 1536*256 -> 196608 floats
#define OFF_WPB     265728u     // bf16 256*512  -> 65536 floats
#define OFF_XMT     331264u     // bf16 8*1024*256 -> 1048576 floats
#define OFF_Q       1379840u    // bf16 64*1024*64 -> 2097152 floats
#define OFF_K       3476992u
#define OFF_V       5574144u    // bf16 transposed [head][d][l]
#define OFF_O       7671296u    // bf16 [n][l][512] -> 2097152 floats
// total 9768448 floats = 39.1 MB

typedef __bf16 bf16x8 __attribute__((ext_vector_type(8)));
typedef __bf16 bf16x4 __attribute__((ext_vector_type(4)));
typedef short s16x4 __attribute__((ext_vector_type(4)));
typedef short s16x8 __attribute__((ext_vector_type(8)));
typedef float f32x4 __attribute__((ext_vector_type(4)));

// ---------------- fused prep: wq-norm | wp-norm | rope | style in one launch ----------------
__global__ __launch_bounds__(256) void k_prep(
    const float* __restrict__ w, const float* __restrict__ mod_w, float* __restrict__ style,
    const float* __restrict__ qkv_w, const float* __restrict__ gain,
    const float* __restrict__ bias, __hip_bfloat16* __restrict__ wqb, float* __restrict__ biasg,
    const float* __restrict__ proj_w, const float* __restrict__ rgain,
    __hip_bfloat16* __restrict__ wpb,
    float* __restrict__ cosT, float* __restrict__ sinT) {
    int bid = blockIdx.x;
    int t = threadIdx.x;
    int wv = t >> 6, lane = t & 63;
    if (bid < 384) {
        int o = bid * 4 + wv;
        float4 v = *reinterpret_cast<const float4*>(qkv_w + o * CC + lane * 4);
        float s = v.x + v.y + v.z + v.w;
        #pragma unroll
        for (int off = 1; off < 64; off <<= 1) s += __shfl_xor(s, off);
        float mean = s * (1.0f / 256.0f);
        float c0 = v.x - mean, c1 = v.y - mean, c2 = v.z - mean, c3 = v.w - mean;
        float ss = c0 * c0 + c1 * c1 + c2 * c2 + c3 * c3;
        #pragma unroll
        for (int off = 1; off < 64; off <<= 1) ss += __shfl_xor(ss, off);
        float g = gain[o];
        float scale = g / ((sqrtf(ss) + 1e-8f) * 16.0f);
        bf16x4 outv;
        outv[0] = (__bf16)(c0 * scale); outv[1] = (__bf16)(c1 * scale);
        outv[2] = (__bf16)(c2 * scale); outv[3] = (__bf16)(c3 * scale);
        *reinterpret_cast<bf16x4*>((__bf16*)wqb + o * CC + lane * 4) = outv;
        if (lane == 0) biasg[o] = bias[o] * g;
    } else if (bid < 448) {
        int r = (bid - 384) * 4 + wv;
        const float* p = proj_w + r * 512 + lane * 8;
        float4 v0 = *reinterpret_cast<const float4*>(p);
        float4 v1 = *reinterpret_cast<const float4*>(p + 4);
        float s = v0.x + v0.y + v0.z + v0.w + v1.x + v1.y + v1.z + v1.w;
        #pragma unroll
        for (int off = 1; off < 64; off <<= 1) s += __shfl_xor(s, off);
        float mean = s * (1.0f / 512.0f);
        float c[8] = {v0.x - mean, v0.y - mean, v0.z - mean, v0.w - mean,
                      v1.x - mean, v1.y - mean, v1.z - mean, v1.w - mean};
        float ss = 0.f;
        #pragma unroll
        for (int i = 0; i < 8; ++i) ss += c[i] * c[i];
        #pragma unroll
        for (int off = 1; off < 64; off <<= 1) ss += __shfl_xor(ss, off);
        float scale = rgain[r] / ((sqrtf(ss) + 1e-8f) * 22.62741699796952f);
        bf16x8 outv;
        #pragma unroll
        for (int i = 0; i < 8; ++i) outv[i] = (__bf16)(c[i] * scale);
        *reinterpret_cast<bf16x8*>((__bf16*)wpb + r * 512 + lane * 8) = outv;
    } else if (bid < 512) {
        int idx = (bid - 448) * 256 + t;
        int l = idx >> 4, j = idx & 15;
        int hh = l >> 5, ww = l & 31;
        float f = exp2f(-(float)j * 0.8304820238941836f);
        float s1, c1, s2, c2;
        __sincosf((float)hh * f, &s1, &c1);
        __sincosf((float)ww * f, &s2, &c2);
        cosT[l * 32 + j]      = c1;
        sinT[l * 32 + j]      = s1;
        cosT[l * 32 + 16 + j] = c2;
        sinT[l * 32 + 16 + j] = s2;
    } else {
        int b = bid - 512;
        int n = b >> 2, cg = b & 3;
        int c = cg * 64 + lane;
        __shared__ float red[4][64];
        float acc = 0.f;
        #pragma unroll 8
        for (int e = wv * 128; e < wv * 128 + 128; ++e)
            acc += w[n * EE + e] * mod_w[e * CC + c];
        red[wv][lane] = acc;
        __syncthreads();
        if (wv == 0)
            style[n * CC + c] = red[0][lane] + red[1][lane] + red[2][lane] + red[3][lane] + 1.0f;
    }
}

// ------------- prep: xmT[n][l][c] = bf16(x[n][c][l] * style[n][c]) -------------
__global__ __launch_bounds__(256) void k_xm(const float* __restrict__ x,
                                            const float* __restrict__ style,
                                            __hip_bfloat16* __restrict__ xmT) {
    int lb = blockIdx.x;   // 16
    int cb = blockIdx.y;   // 4
    int n  = blockIdx.z;   // 8
    int t = threadIdx.x;
    __shared__ float tile[64][68];
    int r = t >> 2, q = t & 3;
    float st = style[n * CC + cb * 64 + r];
    const float* xp = x + (size_t)n * (CC * LL) + (size_t)(cb * 64 + r) * LL + lb * 64 + q * 16;
    #pragma unroll
    for (int i = 0; i < 4; ++i) {
        float4 v = *reinterpret_cast<const float4*>(xp + i * 4);
        tile[r][q * 16 + i * 4 + 0] = v.x * st;
        tile[r][q * 16 + i * 4 + 1] = v.y * st;
        tile[r][q * 16 + i * 4 + 2] = v.z * st;
        tile[r][q * 16 + i * 4 + 3] = v.w * st;
    }
    __syncthreads();
    __hip_bfloat16 outv[16];
    #pragma unroll
    for (int i = 0; i < 16; ++i)
        outv[i] = __float2bfloat16(tile[q * 16 + i][r]);
    __hip_bfloat16* dst = xmT + (size_t)n * (LL * CC) + (size_t)(lb * 64 + r) * CC + cb * 64 + q * 16;
    *reinterpret_cast<bf16x8*>(dst)     = *reinterpret_cast<bf16x8*>(&outv[0]);
    *reinterpret_cast<bf16x8*>(dst + 8) = *reinterpret_cast<bf16x8*>(&outv[8]);
}

// ------------- QKV MFMA GEMM, LDS-staged, single-barrier dbuf + fused epilogue -------------
// Q rows are pre-scaled by 8*log2(e) so attention's exp2 needs no fma.
__global__ __launch_bounds__(256) void k_qkv3(const __hip_bfloat16* __restrict__ wqb,
                                              const __hip_bfloat16* __restrict__ xmT,
                                              const float* __restrict__ biasg,
                                              const float* __restrict__ cosT,
                                              const float* __restrict__ sinT,
                                              __hip_bfloat16* __restrict__ qb,
                                              __hip_bfloat16* __restrict__ kb,
                                              __hip_bfloat16* __restrict__ vt) {
    int lb = blockIdx.x;   // 8
    int ob = blockIdx.y;   // 12
    int n  = blockIdx.z;   // 8
    int tid = threadIdx.x;
    int wid = tid >> 6, lane = tid & 63;
    int wr = wid >> 1, wc = wid & 1;
    int g = lane >> 4, r16 = lane & 15;

    int o0 = ob * 128 + wr * 64;
    int l0 = lb * 128 + wc * 64;
    int part = o0 >> 9;
    int h = (o0 & 511) >> 6;

    __shared__ __hip_bfloat16 smem[32768];

    const int srow[4] = {tid >> 3, (tid + 256) >> 3, (tid + 512) >> 3, (tid + 768) >> 3};
    const int scol = (tid & 7) * 8;
    int sswz[4];
    #pragma unroll
    for (int i = 0; i < 4; ++i) sswz[i] = scol ^ ((srow[i] & 7) << 3);

    const __hip_bfloat16* Agl = wqb + (size_t)(ob * 128) * CC;
    const __hip_bfloat16* Bgl = xmT + (size_t)n * (LL * CC) + (size_t)(lb * 128) * CC;

    bf16x8 ar[4], br[4];
    #pragma unroll
    for (int i = 0; i < 4; ++i) {
        ar[i] = *reinterpret_cast<const bf16x8*>(Agl + (size_t)srow[i] * CC + scol);
        br[i] = *reinterpret_cast<const bf16x8*>(Bgl + (size_t)srow[i] * CC + scol);
    }
    #pragma unroll
    for (int i = 0; i < 4; ++i) {
        *reinterpret_cast<bf16x8*>(&smem[srow[i] * 64 + sswz[i]]) = ar[i];
        *reinterpret_cast<bf16x8*>(&smem[16384 + srow[i] * 64 + sswz[i]]) = br[i];
    }
    __syncthreads();

    f32x4 acc[4][4] = {};
    int cur = 0;
    for (int t = 0; t < 4; ++t) {
        if (t < 3) {
            int kt1 = (t + 1) * 64;
            #pragma unroll
            for (int i = 0; i < 4; ++i) {
                ar[i] = *reinterpret_cast<const bf16x8*>(Agl + (size_t)srow[i] * CC + kt1 + scol);
                br[i] = *reinterpret_cast<const bf16x8*>(Bgl + (size_t)srow[i] * CC + kt1 + scol);
            }
        }
        const __hip_bfloat16* At = &smem[cur * 8192];
        const __hip_bfloat16* Bt = &smem[16384 + cur * 8192];
        #pragma unroll
        for (int kk = 0; kk < 2; ++kk) {
            int col = (kk * 32 + g * 8) ^ ((r16 & 7) << 3);
            bf16x8 a[4], b[4];
            #pragma unroll
            for (int m = 0; m < 4; ++m)
                a[m] = *reinterpret_cast<const bf16x8*>(&At[(wr * 64 + m * 16 + r16) * 64 + col]);
            #pragma unroll
            for (int nn = 0; nn < 4; ++nn)
                b[nn] = *reinterpret_cast<const bf16x8*>(&Bt[(wc * 64 + nn * 16 + r16) * 64 + col]);
            __builtin_amdgcn_s_setprio(1);
            #pragma unroll
            for (int m = 0; m < 4; ++m)
                #pragma unroll
                for (int nn = 0; nn < 4; ++nn)
                    acc[m][nn] = __builtin_amdgcn_mfma_f32_16x16x32_bf16(a[m], b[nn], acc[m][nn], 0, 0, 0);
            __builtin_amdgcn_s_setprio(0);
        }
        if (t < 3) {
            #pragma unroll
            for (int i = 0; i < 4; ++i) {
                *reinterpret_cast<bf16x8*>(&smem[(cur ^ 1) * 8192 + srow[i] * 64 + sswz[i]]) = ar[i];
                *reinterpret_cast<bf16x8*>(&smem[16384 + (cur ^ 1) * 8192 + srow[i] * 64 + sswz[i]]) = br[i];
            }
        }
        __syncthreads();
        cur ^= 1;
    }

    __hip_bfloat16 (*sw)[64][72] = reinterpret_cast<__hip_bfloat16 (*)[64][72]>(smem);

    float bg[4][4];
    #pragma unroll
    for (int m = 0; m < 4; ++m)
        #pragma unroll
        for (int reg = 0; reg < 4; ++reg)
            bg[m][reg] = biasg[o0 + m * 16 + 4 * g + reg];

    size_t head = (size_t)(n * 8 + h);

    if (part < 2) {
        __hip_bfloat16* dst = (part == 0) ? qb : kb;
        float qscale = (part == 0) ? 11.541560327111707f : 1.0f;  // 8*log2(e) folded into Q
        #pragma unroll
        for (int nn = 0; nn < 4; ++nn) {
            int l = l0 + nn * 16 + r16;
            float rv[4][4];
            float ss = 0.f;
            #pragma unroll
            for (int m = 0; m < 4; ++m) {
                int j0 = m * 8 + g * 2;
                float cA = cosT[l * 32 + j0],     sA = sinT[l * 32 + j0];
                float cB = cosT[l * 32 + j0 + 1], sB = sinT[l * 32 + j0 + 1];
                float x0 = acc[m][nn][0] + bg[m][0];
                float x1 = acc[m][nn][1] + bg[m][1];
                float x2 = acc[m][nn][2] + bg[m][2];
                float x3 = acc[m][nn][3] + bg[m][3];
                rv[m][0] = x0 * cA - x1 * sA;
                rv[m][1] = x0 * sA + x1 * cA;
                rv[m][2] = x2 * cB - x3 * sB;
                rv[m][3] = x2 * sB + x3 * cB;
                ss += rv[m][0] * rv[m][0] + rv[m][1] * rv[m][1] +
                      rv[m][2] * rv[m][2] + rv[m][3] * rv[m][3];
            }
            ss += __shfl_xor(ss, 16);
            ss += __shfl_xor(ss, 32);
            float inv = qscale / (sqrtf(ss) + 1e-8f);
            #pragma unroll
            for (int m = 0; m < 4; ++m)
                #pragma unroll
                for (int reg = 0; reg < 4; ++reg)
                    sw[wid][nn * 16 + r16][m * 16 + 4 * g + reg] =
                        __float2bfloat16(rv[m][reg] * inv);
        }
        #pragma unroll
        for (int it = 0; it < 8; ++it) {
            int idx = lane + it * 64;
            int ll = idx >> 3, ch = idx & 7;
            bf16x8 v = *reinterpret_cast<bf16x8*>(&sw[wid][ll][ch * 8]);
            *reinterpret_cast<bf16x8*>(dst + (head * LL + l0 + ll) * DH + ch * 8) = v;
        }
    } else {
        #pragma unroll
        for (int nn = 0; nn < 4; ++nn)
            #pragma unroll
            for (int m = 0; m < 4; ++m)
                #pragma unroll
                for (int reg = 0; reg < 4; ++reg)
                    sw[wid][m * 16 + 4 * g + reg][nn * 16 + r16] =
                        __float2bfloat16(acc[m][nn][reg] + bg[m][reg]);
        #pragma unroll
        for (int it = 0; it < 8; ++it) {
            int idx = lane + it * 64;
            int dd = idx >> 3, ch = idx & 7;
            bf16x8 v = *reinterpret_cast<bf16x8*>(&sw[wid][dd][ch * 8]);
            *reinterpret_cast<bf16x8*>(vt + (head * DH + dd) * LL + l0 + ch * 8) = v;
        }
    }
}

// ------------- MFMA flash attention: 32 q/wave, KVBLK=128 (2x64 sub-tiles), 1 barrier/tile -------------
// Q pre-scaled by 8*log2e => p = exp2(sacc), no per-score fma. 0-conflict swizzles. (R15 form)
__global__ __launch_bounds__(256) void k_attn_mfma(
    const __hip_bfloat16* __restrict__ qb, const __hip_bfloat16* __restrict__ kb,
    const __hip_bfloat16* __restrict__ vt, const float* __restrict__ sinks,
    __hip_bfloat16* __restrict__ ob) {
    int bid = blockIdx.x;                       // 512
    int swz = (bid & 7) * 64 + (bid >> 3);      // XCD x owns one n
    int n    = swz >> 6;
    int h    = (swz >> 3) & 7;
    int qblk = swz & 7;
    int tid  = threadIdx.x;
    int wid  = tid >> 6, lane = tid & 63;
    int g = lane >> 4, r16 = lane & 15;

    size_t head = (size_t)(n * 8 + h);
    const __hip_bfloat16* Q = qb + head * (size_t)(LL * DH);
    const __hip_bfloat16* K = kb + head * (size_t)(LL * DH);
    const __hip_bfloat16* V = vt + head * (size_t)(DH * LL);   // [d][l]
    __hip_bfloat16* O = ob + (size_t)n * (LL * 512) + h * 64;  // [l][512]

    int q0 = qblk * 128 + wid * 32;

    // KVBLK=128 tiles, double-buffered: K [128][64], V [64][128]
    __shared__ __hip_bfloat16 kls[2][128][64];
    __shared__ __hip_bfloat16 vls[2][64][128];

    const int kcl = tid >> 3, kcd = (tid & 7) * 8;
    const int vcl = tid >> 4, vcd = (tid & 15) * 8;
    int kswz[4], vswzA[4], vswzB[4];
    #pragma unroll
    for (int i = 0; i < 4; ++i) {
        kswz[i]  = kcd ^ (((kcl + i * 32) & 7) << 3);
        vswzA[i] = vcd ^ (((vcl + i * 16) & 15) << 2);
        vswzB[i] = (vcd + 4) ^ (((vcl + i * 16) & 15) << 2);
    }

    bf16x8 qf[2][2];
    #pragma unroll
    for (int qm = 0; qm < 2; ++qm)
        #pragma unroll
        for (int dc = 0; dc < 2; ++dc)
            qf[qm][dc] = *reinterpret_cast<const bf16x8*>(
                Q + (size_t)(q0 + qm * 16 + r16) * DH + dc * 32 + g * 8);

    float snk = sinks[h];

    f32x4 oacc[2][4];
    #pragma unroll
    for (int qm = 0; qm < 2; ++qm)
        #pragma unroll
        for (int dn = 0; dn < 4; ++dn)
            oacc[qm][dn] = (f32x4){0.f, 0.f, 0.f, 0.f};
    f32x4 osum[2];
    osum[0] = (f32x4){0.f, 0.f, 0.f, 0.f};
    osum[1] = (f32x4){0.f, 0.f, 0.f, 0.f};
    const s16x4 ones = {(short)0x3F80, (short)0x3F80, (short)0x3F80, (short)0x3F80};

    bf16x8 kr[4], vr[4];
    #pragma unroll
    for (int i = 0; i < 4; ++i) {
        kr[i] = *reinterpret_cast<const bf16x8*>(K + (size_t)(kcl + i * 32) * DH + kcd);
        vr[i] = *reinterpret_cast<const bf16x8*>(V + (size_t)(vcl + i * 16) * LL + vcd);
    }
    #pragma unroll
    for (int i = 0; i < 4; ++i) {
        *reinterpret_cast<bf16x8*>(&kls[0][kcl + i * 32][kswz[i]]) = kr[i];
        s16x8 wv8 = __builtin_bit_cast(s16x8, vr[i]);
        *reinterpret_cast<s16x4*>(&vls[0][vcl + i * 16][vswzA[i]]) = __builtin_shufflevector(wv8, wv8, 0, 1, 2, 3);
        *reinterpret_cast<s16x4*>(&vls[0][vcl + i * 16][vswzB[i]]) = __builtin_shufflevector(wv8, wv8, 4, 5, 6, 7);
    }
    __syncthreads();

    int cur = 0;
    for (int t = 0; t < 8; ++t) {
        if (t < 7) {
            int kt1 = (t + 1) * 128;
            #pragma unroll
            for (int i = 0; i < 4; ++i) {
                kr[i] = *reinterpret_cast<const bf16x8*>(K + (size_t)(kt1 + kcl + i * 32) * DH + kcd);
                vr[i] = *reinterpret_cast<const bf16x8*>(V + (size_t)(vcl + i * 16) * LL + kt1 + vcd);
            }
        }
        #pragma unroll
        for (int sub = 0; sub < 2; ++sub) {
            f32x4 sacc[2][4];
            #pragma unroll
            for (int qm = 0; qm < 2; ++qm)
                #pragma unroll
                for (int kn = 0; kn < 4; ++kn)
                    sacc[qm][kn] = (f32x4){0.f, 0.f, 0.f, 0.f};
            __builtin_amdgcn_s_setprio(1);
            #pragma unroll
            for (int kn = 0; kn < 4; ++kn) {
                int krow = sub * 64 + kn * 16 + r16;
                #pragma unroll
                for (int dc = 0; dc < 2; ++dc) {
                    bf16x8 kf = *reinterpret_cast<const bf16x8*>(
                        &kls[cur][krow][(dc * 32 + g * 8) ^ ((r16 & 7) << 3)]);
                    #pragma unroll
                    for (int qm = 0; qm < 2; ++qm)
                        sacc[qm][kn] = __builtin_amdgcn_mfma_f32_16x16x32_bf16(
                            kf, qf[qm][dc], sacc[qm][kn], 0, 0, 0);
                }
            }
            __builtin_amdgcn_s_setprio(0);
            #pragma unroll
            for (int kn = 0; kn < 4; ++kn) {
                s16x4 pa[2];
                #pragma unroll
                for (int qm = 0; qm < 2; ++qm) {
                    // Q pre-scaled: p = exp2(sacc), no fma
                    float p0 = exp2f(sacc[qm][kn][0]);
                    float p1 = exp2f(sacc[qm][kn][1]);
                    float p2 = exp2f(sacc[qm][kn][2]);
                    float p3 = exp2f(sacc[qm][kn][3]);
                    bf16x4 pb;
                    pb[0] = (__bf16)p0; pb[1] = (__bf16)p1;
                    pb[2] = (__bf16)p2; pb[3] = (__bf16)p3;
                    pa[qm] = __builtin_bit_cast(s16x4, pb);
                }
                __builtin_amdgcn_s_setprio(1);
                #pragma unroll
                for (int qm = 0; qm < 2; ++qm)
                    osum[qm] = __builtin_amdgcn_mfma_f32_16x16x16bf16_1k(pa[qm], ones, osum[qm], 0, 0, 0);
                #pragma unroll
                for (int dn = 0; dn < 4; ++dn) {
                    int vcol = sub * 64 + kn * 16 + g * 4;
                    s16x4 vb = *reinterpret_cast<const s16x4*>(
                        &vls[cur][dn * 16 + r16][vcol ^ ((r16 & 15) << 2)]);
                    #pragma unroll
                    for (int qm = 0; qm < 2; ++qm)
                        oacc[qm][dn] = __builtin_amdgcn_mfma_f32_16x16x16bf16_1k(
                            pa[qm], vb, oacc[qm][dn], 0, 0, 0);
                }
                __builtin_amdgcn_s_setprio(0);
            }
        }
        if (t < 7) {
            #pragma unroll
            for (int i = 0; i < 4; ++i) {
                *reinterpret_cast<bf16x8*>(&kls[cur ^ 1][kcl + i * 32][kswz[i]]) = kr[i];
                s16x8 wv8 = __builtin_bit_cast(s16x8, vr[i]);
                *reinterpret_cast<s16x4*>(&vls[cur ^ 1][vcl + i * 16][vswzA[i]]) = __builtin_shufflevector(wv8, wv8, 0, 1, 2, 3);
                *reinterpret_cast<s16x4*>(&vls[cur ^ 1][vcl + i * 16][vswzB[i]]) = __builtin_shufflevector(wv8, wv8, 4, 5, 6, 7);
            }
        }
        __syncthreads();
        cur ^= 1;
    }

    // osum[qm][reg] = rowsum for q = qm*16 + 4g+reg; p unshifted => sink term unshifted
    float sink_e = exp2f(snk * 1.44269504f);
    #pragma unroll
    for (int qm = 0; qm < 2; ++qm) {
        #pragma unroll
        for (int reg = 0; reg < 4; ++reg) {
            float invq = 1.0f / (osum[qm][reg] + sink_e);
            #pragma unroll
            for (int dn = 0; dn < 4; ++dn)
                O[(size_t)(q0 + qm * 16 + 4 * g + reg) * 512 + dn * 16 + r16] =
                    __float2bfloat16(oacc[qm][dn][reg] * invq);
        }
    }
}

// ------------- output projection MFMA: 64x64 tiles (2+ blocks/CU), dbuf + residual -------------
__global__ __launch_bounds__(256) void k_proj4(const __hip_bfloat16* __restrict__ wpb,
                                               const __hip_bfloat16* __restrict__ ob,
                                               const float* __restrict__ x,
                                               float* __restrict__ out) {
    int lb = blockIdx.x;   // 16 (l blocks of 64)
    int cb = blockIdx.y;   // 4  (c blocks of 64)
    int n  = blockIdx.z;   // 8
    int tid = threadIdx.x;
    int wid = tid >> 6, lane = tid & 63;
    int wr = wid >> 1, wc = wid & 1;
    int g = lane >> 4, r16 = lane & 15;

    int c0 = cb * 64 + wr * 32;
    int l0 = lb * 64 + wc * 32;

    // 32 KB shared: A[2] el 0/4096, B[2] el 8192/12288
    __shared__ __hip_bfloat16 smem[16384];

    // staging: A and B each 64 rows x 64 cols -> 512 chunks of 8, 2 per thread
    const int srow[2] = {tid >> 3, (tid + 256) >> 3};
    const int scol = (tid & 7) * 8;
    int sswz[2];
    #pragma unroll
    for (int i = 0; i < 2; ++i) sswz[i] = scol ^ ((srow[i] & 7) << 3);

    const __hip_bfloat16* Agl = wpb + (size_t)(cb * 64) * 512;
    const __hip_bfloat16* Bgl = ob + (size_t)n * (LL * 512) + (size_t)(lb * 64) * 512;

    bf16x8 ar[2], br[2];
    #pragma unroll
    for (int i = 0; i < 2; ++i) {
        ar[i] = *reinterpret_cast<const bf16x8*>(Agl + (size_t)srow[i] * 512 + scol);
        br[i] = *reinterpret_cast<const bf16x8*>(Bgl + (size_t)srow[i] * 512 + scol);
    }
    #pragma unroll
    for (int i = 0; i < 2; ++i) {
        *reinterpret_cast<bf16x8*>(&smem[srow[i] * 64 + sswz[i]]) = ar[i];
        *reinterpret_cast<bf16x8*>(&smem[8192 + srow[i] * 64 + sswz[i]]) = br[i];
    }
    __syncthreads();

    f32x4 acc[2][2] = {};
    int cur = 0;
    for (int t = 0; t < 8; ++t) {
        if (t < 7) {
            int kt1 = (t + 1) * 64;
            #pragma unroll
            for (int i = 0; i < 2; ++i) {
                ar[i] = *reinterpret_cast<const bf16x8*>(Agl + (size_t)srow[i] * 512 + kt1 + scol);
                br[i] = *reinterpret_cast<const bf16x8*>(Bgl + (size_t)srow[i] * 512 + kt1 + scol);
            }
        }
        const __hip_bfloat16* At = &smem[cur * 4096];
        const __hip_bfloat16* Bt = &smem[8192 + cur * 4096];
        #pragma unroll
        for (int kk = 0; kk < 2; ++kk) {
            int col = (kk * 32 + g * 8) ^ ((r16 & 7) << 3);
            bf16x8 a[2], b[2];
            #pragma unroll
            for (int m = 0; m < 2; ++m)
                a[m] = *reinterpret_cast<const bf16x8*>(&At[(wr * 32 + m * 16 + r16) * 64 + col]);
            #pragma unroll
            for (int nn = 0; nn < 2; ++nn)
                b[nn] = *reinterpret_cast<const bf16x8*>(&Bt[(wc * 32 + nn * 16 + r16) * 64 + col]);
            __builtin_amdgcn_s_setprio(1);
            #pragma unroll
            for (int m = 0; m < 2; ++m)
                #pragma unroll
                for (int nn = 0; nn < 2; ++nn)
                    acc[m][nn] = __builtin_amdgcn_mfma_f32_16x16x32_bf16(a[m], b[nn], acc[m][nn], 0, 0, 0);
            __builtin_amdgcn_s_setprio(0);
        }
        if (t < 7) {
            #pragma unroll
            for (int i = 0; i < 2; ++i) {
                *reinterpret_cast<bf16x8*>(&smem[(cur ^ 1) * 4096 + srow[i] * 64 + sswz[i]]) = ar[i];
                *reinterpret_cast<bf16x8*>(&smem[8192 + (cur ^ 1) * 4096 + srow[i] * 64 + sswz[i]]) = br[i];
            }
        }
        __syncthreads();
        cur ^= 1;
    }

    #pragma unroll
    for (int m = 0; m < 2; ++m) {
        #pragma unroll
        for (int reg = 0; reg < 4; ++reg) {
            int c = c0 + m * 16 + 4 * g + reg;
            #pragma unroll
            for (int nn = 0; nn < 2; ++nn) {
                int l = l0 + nn * 16 + r16;
                size_t idx = (size_t)n * (CC * LL) + (size_t)c * LL + l;
                out[idx] = x[idx] + acc[m][nn][reg];
            }
        }
    }
}

extern "C" void kernel_launch(void* const* d_in, const int* in_sizes, int n_in,
                              void* d_out, int out_size, void* d_ws, size_t ws_size,
                              hipStream_t stream) {
    const float* x       = (const float*)d_in[0];
    const float* w       = (const float*)d_in[1];
    const float* igain   = (const float*)d_in[2];
    const float* rgain   = (const float*)d_in[3];
    const float* qkv_w   = (const float*)d_in[4];
    const float* qkv_b   = (const float*)d_in[5];
    const float* mod_w   = (const float*)d_in[6];
    const float* proj_w  = (const float*)d_in[7];
    const float* sinks   = (const float*)d_in[8];
    float* out = (float*)d_out;
    float* ws  = (float*)d_ws;

    float* style = ws + OFF_STYLE;
    float* biasg = ws + OFF_BIAS;
    float* cosT  = ws + OFF_COS;
    float* sinT  = ws + OFF_SIN;
    __hip_bfloat16* wqb = (__hip_bfloat16*)(ws + OFF_WQB);
    __hip_bfloat16* wpb = (__hip_bfloat16*)(ws + OFF_WPB);
    __hip_bfloat16* xmT = (__hip_bfloat16*)(ws + OFF_XMT);
    __hip_bfloat16* qb  = (__hip_bfloat16*)(ws + OFF_Q);
    __hip_bfloat16* kb  = (__hip_bfloat16*)(ws + OFF_K);
    __hip_bfloat16* vt  = (__hip_bfloat16*)(ws + OFF_V);
    __hip_bfloat16* obuf = (__hip_bfloat16*)(ws + OFF_O);

    k_prep<<<544, 256, 0, stream>>>(w, mod_w, style, qkv_w, igain, qkv_b, wqb, biasg,
                                    proj_w, rgain, wpb, cosT, sinT);
    k_xm<<<dim3(16, 4, NN), 256, 0, stream>>>(x, style, xmT);
    k_qkv3<<<dim3(8, 12, NN), 256, 0, stream>>>(wqb, xmT, biasg, cosT, sinT, qb, kb, vt);
    k_attn_mfma<<<512, 256, 0, stream>>>(qb, kb, vt, sinks, obuf);
    k_proj4<<<dim3(16, 4, NN), 256, 0, stream>>>(wpb, obuf, x, out);
}